// Round 1
// baseline (472.629 us; speedup 1.0000x reference)
//
#include <hip/hip_runtime.h>
#include <math.h>

#define WST 65  // 49x64 k-window tile, stride 65: (w*65+d)%32 distinct -> conflict-free

__device__ __forceinline__ float sigm(float x)  { return 1.0f / (1.0f + __expf(-x)); }
__device__ __forceinline__ float siluf(float x) { return x * sigm(x); }

__device__ __forceinline__ float wredsum(float v) {
#pragma unroll
    for (int off = 32; off; off >>= 1) v += __shfl_xor(v, off);
    return v;
}

// ---------------- tiled fp32 GEMM, 64x64 tile, 4x4 microtile, fused epilogue -------------
// GATE=0: C = silu(A@B)        GATE=1: g = sigmoid(silu(A@B + bias)); C = g*v + (1-g)*o
template <int GATE>
__global__ __launch_bounds__(256) void gemm_ep(
    const float* __restrict__ A, int lda,
    const float* __restrict__ Bw, int ldb,   // K x N row-major, K = 256
    float* __restrict__ Cc, int ldc,
    const float* __restrict__ bias,
    const float* __restrict__ vbuf,          // stride 768
    const float* __restrict__ obuf)          // stride 256
{
    __shared__ float As[16][68];  // transposed A tile [k][m]; stride 68 keeps float4 reads 16B-aligned
    __shared__ float Bs[16][64];
    const int t  = threadIdx.x;
    const int m0 = blockIdx.y << 6, n0 = blockIdx.x << 6;
    const int tx = t & 15, ty = t >> 4;
    const int ar = t >> 2, ac = (t & 3) << 2;   // A tile: 64 rows x 16 k
    const int br = t >> 4, bc = (t & 15) << 2;  // B tile: 16 k x 64 cols
    const float* Ap = A + (m0 + ar) * lda + ac;
    const float* Bp = Bw + br * ldb + n0 + bc;
    float acc[4][4] = {};
    for (int k0 = 0; k0 < 256; k0 += 16) {
        float4 av = *(const float4*)(Ap + k0);
        float4 bv = *(const float4*)(Bp + k0 * ldb);
        As[ac + 0][ar] = av.x; As[ac + 1][ar] = av.y;
        As[ac + 2][ar] = av.z; As[ac + 3][ar] = av.w;
        *(float4*)&Bs[br][bc] = bv;
        __syncthreads();
#pragma unroll
        for (int kk = 0; kk < 16; ++kk) {
            float4 a = *(const float4*)&As[kk][ty << 2];
            float4 b = *(const float4*)&Bs[kk][tx << 2];
            float aa[4] = {a.x, a.y, a.z, a.w};
            float bb[4] = {b.x, b.y, b.z, b.w};
#pragma unroll
            for (int i = 0; i < 4; ++i)
#pragma unroll
                for (int j = 0; j < 4; ++j) acc[i][j] += aa[i] * bb[j];
        }
        __syncthreads();
    }
#pragma unroll
    for (int i = 0; i < 4; ++i) {
        const int m = m0 + (ty << 2) + i;
        const int n = n0 + (tx << 2);
        float rr[4];
        if (GATE) {
            float4 vv = *(const float4*)&vbuf[m * 768 + n];
            float4 ov = *(const float4*)&obuf[m * 256 + n];
            float vvv[4] = {vv.x, vv.y, vv.z, vv.w};
            float ooo[4] = {ov.x, ov.y, ov.z, ov.w};
#pragma unroll
            for (int j = 0; j < 4; ++j) {
                float g = sigm(siluf(acc[i][j] + bias[n + j]));
                rr[j] = g * vvv[j] + (1.f - g) * ooo[j];
            }
        } else {
#pragma unroll
            for (int j = 0; j < 4; ++j) rr[j] = siluf(acc[i][j]);
        }
        float4 r; r.x = rr[0]; r.y = rr[1]; r.z = rr[2]; r.w = rr[3];
        *(float4*)&Cc[m * ldc + n] = r;
    }
}

// ---------------- wp = silu(x@W_wp + b_wp) -> width/sharp ----------------
__global__ __launch_bounds__(256) void wp_kernel(
    const float* __restrict__ x, const float* __restrict__ Wwp,
    const float* __restrict__ bwp, float* __restrict__ width,
    float* __restrict__ sharp)
{
    __shared__ float xs[32][260];
    const int t = threadIdx.x;
    const int row0 = blockIdx.x << 5;
    for (int e = t; e < 2048; e += 256) {   // 32 rows x 64 float4
        int r = e >> 6, cc = (e & 63) << 2;
        *(float4*)&xs[r][cc] = *(const float4*)&x[(row0 + r) * 256 + cc];
    }
    __syncthreads();
    const int rl = t >> 3, n = t & 7;
    float acc = 0.f;
#pragma unroll 8
    for (int k = 0; k < 256; ++k) acc += xs[rl][k] * Wwp[k * 8 + n];
    float s = sigm(siluf(acc + bwp[n]));
    const int row = row0 + rl;
    if (n < 4) width[row * 4 + n] = s * 4.242640687119285f + 0.5f;  // sqrt(18)
    else       sharp[row * 4 + n - 4] = s * 9.5f + 0.5f;
}

// ---------------- rmsnorm(D=64) + RoPE (pos = head index!) for q and k ----------------
__global__ __launch_bounds__(256) void normrope_kernel(
    const float* __restrict__ qkv, const float* __restrict__ wq,
    const float* __restrict__ wk, float* __restrict__ qrot,
    float* __restrict__ krot)
{
    const int row = blockIdx.x;               // b*4096 + l
    const int h = threadIdx.x >> 6, lane = threadIdx.x & 63;
    const int idx = lane & 31;
    const float freq = powf(10000.f, -(float)idx * (1.f / 32.f));
    const float ang = (float)h * freq;        // pos = arange(H) in the reference
    const float cs = cosf(ang), sn = sinf(ang);
#pragma unroll
    for (int which = 0; which < 2; ++which) {
        const float* src = qkv + row * 768 + which * 256 + h * 64 + lane;
        const float* w = which ? wk : wq;
        float v = *src;
        float ss = wredsum(v * v);
        float rms = sqrtf(ss * (1.f / 64.f) + 1e-6f);
        float val = v / rms * w[lane];
        float partner = __shfl_xor(val, 32);
        float out = (lane < 32) ? (val * cs - partner * sn)
                                : (partner * sn + val * cs);
        float* dst = (which ? krot : qrot) + row * 256 + h * 64 + lane;
        *dst = out;
    }
}

// ---------------- local 7x7 attention + fused output rmsnorm(C=256) ----------------
__global__ __launch_bounds__(256) void attn_kernel(
    const float* __restrict__ qrot, const float* __restrict__ krot,
    const float* __restrict__ qkvbuf,
    const float* __restrict__ width, const float* __restrict__ sharp,
    const float* __restrict__ w_onorm, float* __restrict__ attn_out)
{
    __shared__ float ksh[4][49 * WST];  // ~51 KB
    __shared__ float qsh[4][64];
    __shared__ float ash[4][52];
    __shared__ float red[4];
    const int row = blockIdx.x;          // b*4096 + l
    const int b = row >> 12, l = row & 4095;
    const int r = l >> 6, c = l & 63;
    const int h = threadIdx.x >> 6, lane = threadIdx.x & 63;

    qsh[h][lane] = qrot[row * 256 + h * 64 + lane];
    const float* kbase = krot + b * 1048576 + h * 64 + lane;
    for (int w = 0; w < 49; ++w) {       // lane = d; coalesced 256B loads
        int rr = r + (w / 7) - 3, cc = c + (w % 7) - 3;
        float kv = 0.f;
        if ((unsigned)rr < 64u && (unsigned)cc < 64u)
            kv = kbase[(rr * 64 + cc) * 256];
        ksh[h][w * WST + lane] = kv;     // zero-pad OOB windows like unfold2d
    }
    __syncthreads();

    float sv = -3.0e38f;
    if (lane < 49) {                     // lane = window
        const float* kk = &ksh[h][lane * WST];
        const float* qq = qsh[h];
        float acc = 0.f;
#pragma unroll 16
        for (int d = 0; d < 64; ++d) acc += kk[d] * qq[d];
        int di = lane / 7 - 3, dj = lane % 7 - 3;
        float rel = sqrtf((float)(di * di + dj * dj));
        float mask = sigm((width[row * 4 + h] - rel) * sharp[row * 4 + h]);
        sv = acc * 0.125f - (1.f - mask) * 10000.f;
    }
    float m = sv;
#pragma unroll
    for (int off = 32; off; off >>= 1) m = fmaxf(m, __shfl_xor(m, off));
    float p = (lane < 49) ? __expf(sv - m) : 0.f;
    float sum = wredsum(p);
    if (lane < 49) ash[h][lane] = p / sum;
    __syncthreads();

    const float* vbase = qkvbuf + 512 + h * 64 + lane;  // v chunk, row stride 768
    float acc = 0.f;
    for (int w = 0; w < 49; ++w) {       // lane = d; coalesced v reads
        int rr = r + (w / 7) - 3, cc = c + (w % 7) - 3;
        if ((unsigned)rr < 64u && (unsigned)cc < 64u)
            acc += ash[h][w] * vbase[(b * 4096 + rr * 64 + cc) * 768];
    }
    // fused rmsnorm over C=256 (across the 4 waves)
    float sq = wredsum(acc * acc);
    if (lane == 0) red[h] = sq;
    __syncthreads();
    float tot = (red[0] + red[1]) + (red[2] + red[3]);
    float rms = sqrtf(tot * (1.f / 256.f) + 1e-6f);
    attn_out[row * 256 + h * 64 + lane] = acc / rms * w_onorm[h * 64 + lane];
}

extern "C" void kernel_launch(void* const* d_in, const int* in_sizes, int n_in,
                              void* d_out, int out_size, void* d_ws, size_t ws_size,
                              hipStream_t stream)
{
    const float* x      = (const float*)d_in[0];
    const float* W_qkv  = (const float*)d_in[1];
    const float* w_qn   = (const float*)d_in[2];
    const float* w_kn   = (const float*)d_in[3];
    const float* W_wp   = (const float*)d_in[4];
    const float* b_wp   = (const float*)d_in[5];
    const float* w_on   = (const float*)d_in[6];
    const float* W_out  = (const float*)d_in[7];
    const float* W_gate = (const float*)d_in[8];
    const float* b_gate = (const float*)d_in[9];
    float* out = (float*)d_out;

    float* ws     = (float*)d_ws;
    float* qkv    = ws;                    // 8192*768
    float* qrot   = qkv  + 8192 * 768;     // 8192*256
    float* krot   = qrot + 8192 * 256;     // 8192*256
    float* attn_o = krot + 8192 * 256;     // 8192*256
    float* widthp = attn_o + 8192 * 256;   // 8192*4
    float* sharpp = widthp + 8192 * 4;     // 8192*4
    float* merged = qrot;                  // qrot dead after attn_kernel -> reuse

    // qkv = silu(x @ W_qkv)
    gemm_ep<0><<<dim3(12, 128), 256, 0, stream>>>(x, 256, W_qkv, 768, qkv, 768,
                                                  nullptr, nullptr, nullptr);
    // width / sharpness
    wp_kernel<<<256, 256, 0, stream>>>(x, W_wp, b_wp, widthp, sharpp);
    // q/k rmsnorm + rope
    normrope_kernel<<<8192, 256, 0, stream>>>(qkv, w_qn, w_kn, qrot, krot);
    // local attention + output rmsnorm
    attn_kernel<<<8192, 256, 0, stream>>>(qrot, krot, qkv, widthp, sharpp, w_on, attn_o);
    // gate gemm + merge
    gemm_ep<1><<<dim3(4, 128), 256, 0, stream>>>(qkv + 512, 768, W_gate, 256, merged, 256,
                                                 b_gate, qkv + 512, attn_o);
    // final silu(merged @ W_out)
    gemm_ep<0><<<dim3(4, 128), 256, 0, stream>>>(merged, 256, W_out, 256, out, 256,
                                                 nullptr, nullptr, nullptr);
}

// Round 2
// 265.641 us; speedup vs baseline: 1.7792x; 1.7792x over previous
//
#include <hip/hip_runtime.h>
#include <math.h>

#define WST 65  // 49x64 k-window tile, stride 65: (w*65+d)%32 distinct -> conflict-free

__device__ __forceinline__ float sigm(float x)  { return 1.0f / (1.0f + __expf(-x)); }
__device__ __forceinline__ float siluf(float x) { return x * sigm(x); }

__device__ __forceinline__ float wredsum(float v) {
#pragma unroll
    for (int off = 32; off; off >>= 1) v += __shfl_xor(v, off);
    return v;
}

// ---------------- tiled fp32 GEMM, 64x64 tile, 4x4 microtile, fused epilogue -------------
// GATE=0: C = silu(A@B)        GATE=1: g = sigmoid(silu(A@B + bias)); C = g*v + (1-g)*o
template <int GATE>
__global__ __launch_bounds__(256) void gemm_ep(
    const float* __restrict__ A, int lda,
    const float* __restrict__ Bw, int ldb,   // K x N row-major, K = 256
    float* __restrict__ Cc, int ldc,
    const float* __restrict__ bias,
    const float* __restrict__ vbuf,          // stride 768
    const float* __restrict__ obuf)          // stride 256
{
    __shared__ float As[16][68];  // transposed A tile [k][m]; stride 68 keeps float4 reads 16B-aligned
    __shared__ float Bs[16][64];
    const int t  = threadIdx.x;
    const int m0 = blockIdx.y << 6, n0 = blockIdx.x << 6;
    const int tx = t & 15, ty = t >> 4;
    const int ar = t >> 2, ac = (t & 3) << 2;   // A tile: 64 rows x 16 k
    const int br = t >> 4, bc = (t & 15) << 2;  // B tile: 16 k x 64 cols
    const float* Ap = A + (m0 + ar) * lda + ac;
    const float* Bp = Bw + br * ldb + n0 + bc;
    float acc[4][4] = {};
    for (int k0 = 0; k0 < 256; k0 += 16) {
        float4 av = *(const float4*)(Ap + k0);
        float4 bv = *(const float4*)(Bp + k0 * ldb);
        As[ac + 0][ar] = av.x; As[ac + 1][ar] = av.y;
        As[ac + 2][ar] = av.z; As[ac + 3][ar] = av.w;
        *(float4*)&Bs[br][bc] = bv;
        __syncthreads();
#pragma unroll
        for (int kk = 0; kk < 16; ++kk) {
            float4 a = *(const float4*)&As[kk][ty << 2];
            float4 b = *(const float4*)&Bs[kk][tx << 2];
            float aa[4] = {a.x, a.y, a.z, a.w};
            float bb[4] = {b.x, b.y, b.z, b.w};
#pragma unroll
            for (int i = 0; i < 4; ++i)
#pragma unroll
                for (int j = 0; j < 4; ++j) acc[i][j] += aa[i] * bb[j];
        }
        __syncthreads();
    }
#pragma unroll
    for (int i = 0; i < 4; ++i) {
        const int m = m0 + (ty << 2) + i;
        const int n = n0 + (tx << 2);
        float rr[4];
        if (GATE) {
            float4 vv = *(const float4*)&vbuf[m * 768 + n];
            float4 ov = *(const float4*)&obuf[m * 256 + n];
            float vvv[4] = {vv.x, vv.y, vv.z, vv.w};
            float ooo[4] = {ov.x, ov.y, ov.z, ov.w};
#pragma unroll
            for (int j = 0; j < 4; ++j) {
                float g = sigm(siluf(acc[i][j] + bias[n + j]));
                rr[j] = g * vvv[j] + (1.f - g) * ooo[j];
            }
        } else {
#pragma unroll
            for (int j = 0; j < 4; ++j) rr[j] = siluf(acc[i][j]);
        }
        float4 r; r.x = rr[0]; r.y = rr[1]; r.z = rr[2]; r.w = rr[3];
        *(float4*)&Cc[m * ldc + n] = r;
    }
}

// ---------------- wp = silu(x@W_wp + b_wp) -> width/sharp ----------------
__global__ __launch_bounds__(256) void wp_kernel(
    const float* __restrict__ x, const float* __restrict__ Wwp,
    const float* __restrict__ bwp, float* __restrict__ width,
    float* __restrict__ sharp)
{
    __shared__ float xs[32][260];
    const int t = threadIdx.x;
    const int row0 = blockIdx.x << 5;
    for (int e = t; e < 2048; e += 256) {   // 32 rows x 64 float4
        int r = e >> 6, cc = (e & 63) << 2;
        *(float4*)&xs[r][cc] = *(const float4*)&x[(row0 + r) * 256 + cc];
    }
    __syncthreads();
    const int rl = t >> 3, n = t & 7;
    float acc = 0.f;
#pragma unroll 8
    for (int k = 0; k < 256; ++k) acc += xs[rl][k] * Wwp[k * 8 + n];
    float s = sigm(siluf(acc + bwp[n]));
    const int row = row0 + rl;
    if (n < 4) width[row * 4 + n] = s * 4.242640687119285f + 0.5f;  // sqrt(18)
    else       sharp[row * 4 + n - 4] = s * 9.5f + 0.5f;
}

// ---------------- rmsnorm(D=64) + RoPE (pos = head index!) for q and k ----------------
__global__ __launch_bounds__(256) void normrope_kernel(
    const float* __restrict__ qkv, const float* __restrict__ wq,
    const float* __restrict__ wk, float* __restrict__ qrot,
    float* __restrict__ krot)
{
    const int row = blockIdx.x;               // b*4096 + l
    const int h = threadIdx.x >> 6, lane = threadIdx.x & 63;
    const int idx = lane & 31;
    const float freq = powf(10000.f, -(float)idx * (1.f / 32.f));
    const float ang = (float)h * freq;        // pos = arange(H) in the reference
    const float cs = cosf(ang), sn = sinf(ang);
#pragma unroll
    for (int which = 0; which < 2; ++which) {
        const float* src = qkv + row * 768 + which * 256 + h * 64 + lane;
        const float* w = which ? wk : wq;
        float v = *src;
        float ss = wredsum(v * v);
        float rms = sqrtf(ss * (1.f / 64.f) + 1e-6f);
        float val = v / rms * w[lane];
        float partner = __shfl_xor(val, 32);
        float out = (lane < 32) ? (val * cs - partner * sn)
                                : (partner * sn + val * cs);
        float* dst = (which ? krot : qrot) + row * 256 + h * 64 + lane;
        *dst = out;
    }
}

// ---------------- local 7x7 attention + fused output rmsnorm(C=256) ----------------
// R2: register-batched window loads. All 49 k-loads (and later v-loads) are issued
// unconditionally from CLAMPED addresses (no guard branch, no per-iteration waitcnt),
// validity applied as a select afterwards. This turns 98 serialized ~500-cycle
// latencies per block into two pipelined drains.
__global__ __launch_bounds__(256) void attn_kernel(
    const float* __restrict__ qrot, const float* __restrict__ krot,
    const float* __restrict__ qkvbuf,
    const float* __restrict__ width, const float* __restrict__ sharp,
    const float* __restrict__ w_onorm, float* __restrict__ attn_out)
{
    __shared__ float ksh[4][49 * WST];  // ~51 KB -> 3 blocks/CU
    __shared__ float qsh[4][64];
    __shared__ float ash[4][52];
    __shared__ float red[4];
    const int row = blockIdx.x;          // b*4096 + l
    const int b = row >> 12, l = row & 4095;
    const int r = l >> 6, c = l & 63;
    const int h = threadIdx.x >> 6, lane = threadIdx.x & 63;

    qsh[h][lane] = qrot[row * 256 + h * 64 + lane];
    const float* kbase = krot + b * 1048576 + h * 64 + lane;

    // ---- phase 1: k windows -> registers (49 independent loads) -> LDS ----
    float kreg[49];
#pragma unroll
    for (int w = 0; w < 49; ++w) {
        const int rr = r + (w / 7) - 3, cc = c + (w % 7) - 3;
        const int rcl = min(max(rr, 0), 63), ccl = min(max(cc, 0), 63);
        kreg[w] = kbase[(rcl * 64 + ccl) * 256];
    }
#pragma unroll
    for (int w = 0; w < 49; ++w) {
        const int rr = r + (w / 7) - 3, cc = c + (w % 7) - 3;
        const bool valid = ((unsigned)rr < 64u) & ((unsigned)cc < 64u);
        ksh[h][w * WST + lane] = valid ? kreg[w] : 0.f;  // zero-pad like unfold2d
    }
    __syncthreads();

    // ---- issue all 49 v loads now; latency overlaps the score/softmax phase ----
    const float* vbase = qkvbuf + 512 + h * 64 + lane;  // v chunk, row stride 768
    float vreg[49];
#pragma unroll
    for (int w = 0; w < 49; ++w) {
        const int rr = r + (w / 7) - 3, cc = c + (w % 7) - 3;
        const int rcl = min(max(rr, 0), 63), ccl = min(max(cc, 0), 63);
        vreg[w] = vbase[(b * 4096 + rcl * 64 + ccl) * 768];
    }

    // ---- phase 2: scores + masked softmax (lane = window) ----
    float sv = -3.0e38f;
    if (lane < 49) {
        const float* kk = &ksh[h][lane * WST];
        const float* qq = qsh[h];
        float acc = 0.f;
#pragma unroll 16
        for (int d = 0; d < 64; ++d) acc += kk[d] * qq[d];
        int di = lane / 7 - 3, dj = lane % 7 - 3;
        float rel = sqrtf((float)(di * di + dj * dj));
        float mask = sigm((width[row * 4 + h] - rel) * sharp[row * 4 + h]);
        sv = acc * 0.125f - (1.f - mask) * 10000.f;
    }
    float m = sv;
#pragma unroll
    for (int off = 32; off; off >>= 1) m = fmaxf(m, __shfl_xor(m, off));
    float p = (lane < 49) ? __expf(sv - m) : 0.f;
    float sum = wredsum(p);
    if (lane < 49) ash[h][lane] = p / sum;
    __syncthreads();

    // ---- phase 3: PV from registers (lane = d), ash reads are LDS broadcasts ----
    float acc = 0.f;
#pragma unroll
    for (int w = 0; w < 49; ++w) {
        const int rr = r + (w / 7) - 3, cc = c + (w % 7) - 3;
        const bool valid = ((unsigned)rr < 64u) & ((unsigned)cc < 64u);
        acc = fmaf(ash[h][w], valid ? vreg[w] : 0.f, acc);
    }

    // ---- fused rmsnorm over C=256 (across the 4 waves) ----
    float sq = wredsum(acc * acc);
    if (lane == 0) red[h] = sq;
    __syncthreads();
    float tot = (red[0] + red[1]) + (red[2] + red[3]);
    float rms = sqrtf(tot * (1.f / 256.f) + 1e-6f);
    attn_out[row * 256 + h * 64 + lane] = acc / rms * w_onorm[h * 64 + lane];
}

extern "C" void kernel_launch(void* const* d_in, const int* in_sizes, int n_in,
                              void* d_out, int out_size, void* d_ws, size_t ws_size,
                              hipStream_t stream)
{
    const float* x      = (const float*)d_in[0];
    const float* W_qkv  = (const float*)d_in[1];
    const float* w_qn   = (const float*)d_in[2];
    const float* w_kn   = (const float*)d_in[3];
    const float* W_wp   = (const float*)d_in[4];
    const float* b_wp   = (const float*)d_in[5];
    const float* w_on   = (const float*)d_in[6];
    const float* W_out  = (const float*)d_in[7];
    const float* W_gate = (const float*)d_in[8];
    const float* b_gate = (const float*)d_in[9];
    float* out = (float*)d_out;

    float* ws     = (float*)d_ws;
    float* qkv    = ws;                    // 8192*768
    float* qrot   = qkv  + 8192 * 768;     // 8192*256
    float* krot   = qrot + 8192 * 256;     // 8192*256
    float* attn_o = krot + 8192 * 256;     // 8192*256
    float* widthp = attn_o + 8192 * 256;   // 8192*4
    float* sharpp = widthp + 8192 * 4;     // 8192*4
    float* merged = qrot;                  // qrot dead after attn_kernel -> reuse

    // qkv = silu(x @ W_qkv)
    gemm_ep<0><<<dim3(12, 128), 256, 0, stream>>>(x, 256, W_qkv, 768, qkv, 768,
                                                  nullptr, nullptr, nullptr);
    // width / sharpness
    wp_kernel<<<256, 256, 0, stream>>>(x, W_wp, b_wp, widthp, sharpp);
    // q/k rmsnorm + rope
    normrope_kernel<<<8192, 256, 0, stream>>>(qkv, w_qn, w_kn, qrot, krot);
    // local attention + output rmsnorm
    attn_kernel<<<8192, 256, 0, stream>>>(qrot, krot, qkv, widthp, sharpp, w_on, attn_o);
    // gate gemm + merge
    gemm_ep<1><<<dim3(4, 128), 256, 0, stream>>>(qkv + 512, 768, W_gate, 256, merged, 256,
                                                 b_gate, qkv + 512, attn_o);
    // final silu(merged @ W_out)
    gemm_ep<0><<<dim3(4, 128), 256, 0, stream>>>(merged, 256, W_out, 256, out, 256,
                                                 nullptr, nullptr, nullptr);
}

// Round 3
// 220.834 us; speedup vs baseline: 2.1402x; 1.2029x over previous
//
#include <hip/hip_runtime.h>
#include <hip/hip_bf16.h>
#include <math.h>

#define WST 65  // attn k-window tile stride (unchanged this round)

__device__ __forceinline__ float sigm(float x)  { return 1.0f / (1.0f + __expf(-x)); }
__device__ __forceinline__ float siluf(float x) { return x * sigm(x); }

__device__ __forceinline__ float wredsum(float v) {
#pragma unroll
    for (int off = 32; off; off >>= 1) v += __shfl_xor(v, off);
    return v;
}

// ---- bf16 bit helpers (hi/lo split for fp32-accurate MFMA) ----
__device__ __forceinline__ short f2bf(float f) {
    __hip_bfloat16 h = __float2bfloat16(f);
    return *reinterpret_cast<short*>(&h);
}
__device__ __forceinline__ float bf2f(short s) {
    __hip_bfloat16 h = *reinterpret_cast<__hip_bfloat16*>(&s);
    return __bfloat162float(h);
}
__device__ __forceinline__ int pack2(short a, short b) {
    return (int)((unsigned short)a | ((unsigned)(unsigned short)b << 16));
}

typedef short bf16x8 __attribute__((ext_vector_type(8)));
typedef float f32x4  __attribute__((ext_vector_type(4)));

// =======================================================================
// Split-fp32 MFMA GEMM: C = epilogue(A[MxK] @ B[KxN]), K=256, M=8192.
// x = hi + lo (bf16 each); x*w = hi*hi + lo*hi + hi*lo  (lo*lo ~ 2^-16, dropped)
// Tile 128x128, 4 waves each 64x64 (4x4 of 16x16x32), BK=32.
// LDS: hi/lo chunks [128][40] bf16 (stride 40: 80 B rows, 16B-aligned b128,
// bank-start 4(5r+q)%8 -> disjoint quad-spans, 8-cycle optimal).
// GATE=0: C = silu(A@B)   GATE=1: g = sigmoid(silu(A@B+bias)); C = g*v+(1-g)*o
// =======================================================================
template <int GATE>
__global__ __launch_bounds__(256, 2) void gemm_mfma(
    const float* __restrict__ A, int lda,
    const float* __restrict__ Bw, int ldb,
    float* __restrict__ Cc, int ldc,
    const float* __restrict__ bias,
    const float* __restrict__ vbuf,   // stride 768
    const float* __restrict__ obuf)   // stride 256
{
    __shared__ short AsHi[128 * 40], AsLo[128 * 40];
    __shared__ short BsHi[128 * 40], BsLo[128 * 40];   // [n][k] layout

    const int t    = threadIdx.x;
    const int m0   = blockIdx.y << 7, n0 = blockIdx.x << 7;
    const int lane = t & 63;
    const int wave = t >> 6;
    const int wm   = (wave >> 1) << 6, wn = (wave & 1) << 6;
    const int fr   = lane & 15;   // frag row/col
    const int fq   = lane >> 4;   // quad -> k-group (input), row-group (output)

    f32x4 acc[4][4] = {};

    // staging maps
    const int ar  = t >> 3, akc = (t & 7) << 2;   // A: 32 rows/pass x 32 k
    const int bn  = t & 127, bkh = (t >> 7) << 4; // B: 128 n x 16 k per half

    for (int k0 = 0; k0 < 256; k0 += 32) {
        // ---- issue ALL staging loads first (one vmcnt drain) ----
        float4 av[4];
#pragma unroll
        for (int p = 0; p < 4; ++p)
            av[p] = *(const float4*)&A[(size_t)(m0 + (p << 5) + ar) * lda + k0 + akc];
        float bv[16];
#pragma unroll
        for (int i = 0; i < 16; ++i)
            bv[i] = Bw[(size_t)(k0 + bkh + i) * ldb + n0 + bn];

        __syncthreads();   // previous step's LDS reads done before overwrite

        // ---- convert + write A (hi/lo) ----
#pragma unroll
        for (int p = 0; p < 4; ++p) {
            short4 hi, lo;
            hi.x = f2bf(av[p].x); lo.x = f2bf(av[p].x - bf2f(hi.x));
            hi.y = f2bf(av[p].y); lo.y = f2bf(av[p].y - bf2f(hi.y));
            hi.z = f2bf(av[p].z); lo.z = f2bf(av[p].z - bf2f(hi.z));
            hi.w = f2bf(av[p].w); lo.w = f2bf(av[p].w - bf2f(hi.w));
            const int off = ((p << 5) + ar) * 40 + akc;
            *(short4*)&AsHi[off] = hi;
            *(short4*)&AsLo[off] = lo;
        }
        // ---- convert + write B transposed to [n][k] ----
        {
            short sh[16], sl[16];
#pragma unroll
            for (int i = 0; i < 16; ++i) {
                sh[i] = f2bf(bv[i]);
                sl[i] = f2bf(bv[i] - bf2f(sh[i]));
            }
#pragma unroll
            for (int j = 0; j < 2; ++j) {
                int4 ph, pl;
                ph.x = pack2(sh[8*j+0], sh[8*j+1]); pl.x = pack2(sl[8*j+0], sl[8*j+1]);
                ph.y = pack2(sh[8*j+2], sh[8*j+3]); pl.y = pack2(sl[8*j+2], sl[8*j+3]);
                ph.z = pack2(sh[8*j+4], sh[8*j+5]); pl.z = pack2(sl[8*j+4], sl[8*j+5]);
                ph.w = pack2(sh[8*j+6], sh[8*j+7]); pl.w = pack2(sl[8*j+6], sl[8*j+7]);
                const int off = bn * 40 + bkh + (j << 3);
                *(int4*)&BsHi[off] = ph;
                *(int4*)&BsLo[off] = pl;
            }
        }
        __syncthreads();

        // ---- fragments + 3-term MFMA ----
        bf16x8 ah[4], al[4], bh[4], bl[4];
#pragma unroll
        for (int i = 0; i < 4; ++i) {
            const int aoff = (wm + (i << 4) + fr) * 40 + (fq << 3);
            ah[i] = *(const bf16x8*)&AsHi[aoff];
            al[i] = *(const bf16x8*)&AsLo[aoff];
            const int boff = (wn + (i << 4) + fr) * 40 + (fq << 3);
            bh[i] = *(const bf16x8*)&BsHi[boff];
            bl[i] = *(const bf16x8*)&BsLo[boff];
        }
#pragma unroll
        for (int mi = 0; mi < 4; ++mi)
#pragma unroll
            for (int ni = 0; ni < 4; ++ni) {
                acc[mi][ni] = __builtin_amdgcn_mfma_f32_16x16x32_bf16(ah[mi], bh[ni], acc[mi][ni], 0, 0, 0);
                acc[mi][ni] = __builtin_amdgcn_mfma_f32_16x16x32_bf16(al[mi], bh[ni], acc[mi][ni], 0, 0, 0);
                acc[mi][ni] = __builtin_amdgcn_mfma_f32_16x16x32_bf16(ah[mi], bl[ni], acc[mi][ni], 0, 0, 0);
            }
    }

    // ---- epilogue: C/D layout row=(fq*4+reg), col=fr ----
#pragma unroll
    for (int mi = 0; mi < 4; ++mi)
#pragma unroll
        for (int ni = 0; ni < 4; ++ni) {
            const int n = n0 + wn + (ni << 4) + fr;
            const int mb = m0 + wm + (mi << 4) + (fq << 2);
            if (GATE) {
                const float bb = bias[n];
#pragma unroll
                for (int r = 0; r < 4; ++r) {
                    const int m = mb + r;
                    const float g = sigm(siluf(acc[mi][ni][r] + bb));
                    const float vv = vbuf[(size_t)m * 768 + n];
                    const float oo = obuf[(size_t)m * 256 + n];
                    Cc[(size_t)m * ldc + n] = g * vv + (1.f - g) * oo;
                }
            } else {
#pragma unroll
                for (int r = 0; r < 4; ++r) {
                    const int m = mb + r;
                    Cc[(size_t)m * ldc + n] = siluf(acc[mi][ni][r]);
                }
            }
        }
}

// ---------------- wp = silu(x@W_wp + b_wp) -> width/sharp ----------------
__global__ __launch_bounds__(256) void wp_kernel(
    const float* __restrict__ x, const float* __restrict__ Wwp,
    const float* __restrict__ bwp, float* __restrict__ width,
    float* __restrict__ sharp)
{
    __shared__ float xs[32][260];
    const int t = threadIdx.x;
    const int row0 = blockIdx.x << 5;
    for (int e = t; e < 2048; e += 256) {
        int r = e >> 6, cc = (e & 63) << 2;
        *(float4*)&xs[r][cc] = *(const float4*)&x[(row0 + r) * 256 + cc];
    }
    __syncthreads();
    const int rl = t >> 3, n = t & 7;
    float acc = 0.f;
#pragma unroll 8
    for (int k = 0; k < 256; ++k) acc += xs[rl][k] * Wwp[k * 8 + n];
    float s = sigm(siluf(acc + bwp[n]));
    const int row = row0 + rl;
    if (n < 4) width[row * 4 + n] = s * 4.242640687119285f + 0.5f;  // sqrt(18)
    else       sharp[row * 4 + n - 4] = s * 9.5f + 0.5f;
}

// ---------------- rmsnorm(D=64) + RoPE (pos = head index!) for q and k ----------------
__global__ __launch_bounds__(256) void normrope_kernel(
    const float* __restrict__ qkv, const float* __restrict__ wq,
    const float* __restrict__ wk, float* __restrict__ qrot,
    float* __restrict__ krot)
{
    const int row = blockIdx.x;
    const int h = threadIdx.x >> 6, lane = threadIdx.x & 63;
    const int idx = lane & 31;
    const float freq = powf(10000.f, -(float)idx * (1.f / 32.f));
    const float ang = (float)h * freq;        // pos = arange(H) in the reference
    const float cs = cosf(ang), sn = sinf(ang);
#pragma unroll
    for (int which = 0; which < 2; ++which) {
        const float* src = qkv + row * 768 + which * 256 + h * 64 + lane;
        const float* w = which ? wk : wq;
        float v = *src;
        float ss = wredsum(v * v);
        float rms = sqrtf(ss * (1.f / 64.f) + 1e-6f);
        float val = v / rms * w[lane];
        float partner = __shfl_xor(val, 32);
        float out = (lane < 32) ? (val * cs - partner * sn)
                                : (partner * sn + val * cs);
        float* dst = (which ? krot : qrot) + row * 256 + h * 64 + lane;
        *dst = out;
    }
}

// ---------------- local 7x7 attention + fused output rmsnorm(C=256) ----------------
__global__ __launch_bounds__(256) void attn_kernel(
    const float* __restrict__ qrot, const float* __restrict__ krot,
    const float* __restrict__ qkvbuf,
    const float* __restrict__ width, const float* __restrict__ sharp,
    const float* __restrict__ w_onorm, float* __restrict__ attn_out)
{
    __shared__ float ksh[4][49 * WST];
    __shared__ float qsh[4][64];
    __shared__ float ash[4][52];
    __shared__ float red[4];
    const int row = blockIdx.x;
    const int b = row >> 12, l = row & 4095;
    const int r = l >> 6, c = l & 63;
    const int h = threadIdx.x >> 6, lane = threadIdx.x & 63;

    qsh[h][lane] = qrot[row * 256 + h * 64 + lane];
    const float* kbase = krot + b * 1048576 + h * 64 + lane;

    float kreg[49];
#pragma unroll
    for (int w = 0; w < 49; ++w) {
        const int rr = r + (w / 7) - 3, cc = c + (w % 7) - 3;
        const int rcl = min(max(rr, 0), 63), ccl = min(max(cc, 0), 63);
        kreg[w] = kbase[(rcl * 64 + ccl) * 256];
    }
#pragma unroll
    for (int w = 0; w < 49; ++w) {
        const int rr = r + (w / 7) - 3, cc = c + (w % 7) - 3;
        const bool valid = ((unsigned)rr < 64u) & ((unsigned)cc < 64u);
        ksh[h][w * WST + lane] = valid ? kreg[w] : 0.f;
    }
    __syncthreads();

    const float* vbase = qkvbuf + 512 + h * 64 + lane;
    float vreg[49];
#pragma unroll
    for (int w = 0; w < 49; ++w) {
        const int rr = r + (w / 7) - 3, cc = c + (w % 7) - 3;
        const int rcl = min(max(rr, 0), 63), ccl = min(max(cc, 0), 63);
        vreg[w] = vbase[(b * 4096 + rcl * 64 + ccl) * 768];
    }

    float sv = -3.0e38f;
    if (lane < 49) {
        const float* kk = &ksh[h][lane * WST];
        const float* qq = qsh[h];
        float acc = 0.f;
#pragma unroll 16
        for (int d = 0; d < 64; ++d) acc += kk[d] * qq[d];
        int di = lane / 7 - 3, dj = lane % 7 - 3;
        float rel = sqrtf((float)(di * di + dj * dj));
        float mask = sigm((width[row * 4 + h] - rel) * sharp[row * 4 + h]);
        sv = acc * 0.125f - (1.f - mask) * 10000.f;
    }
    float m = sv;
#pragma unroll
    for (int off = 32; off; off >>= 1) m = fmaxf(m, __shfl_xor(m, off));
    float p = (lane < 49) ? __expf(sv - m) : 0.f;
    float sum = wredsum(p);
    if (lane < 49) ash[h][lane] = p / sum;
    __syncthreads();

    float acc = 0.f;
#pragma unroll
    for (int w = 0; w < 49; ++w) {
        const int rr = r + (w / 7) - 3, cc = c + (w % 7) - 3;
        const bool valid = ((unsigned)rr < 64u) & ((unsigned)cc < 64u);
        acc = fmaf(ash[h][w], valid ? vreg[w] : 0.f, acc);
    }

    float sq = wredsum(acc * acc);
    if (lane == 0) red[h] = sq;
    __syncthreads();
    float tot = (red[0] + red[1]) + (red[2] + red[3]);
    float rms = sqrtf(tot * (1.f / 256.f) + 1e-6f);
    attn_out[row * 256 + h * 64 + lane] = acc / rms * w_onorm[h * 64 + lane];
}

extern "C" void kernel_launch(void* const* d_in, const int* in_sizes, int n_in,
                              void* d_out, int out_size, void* d_ws, size_t ws_size,
                              hipStream_t stream)
{
    const float* x      = (const float*)d_in[0];
    const float* W_qkv  = (const float*)d_in[1];
    const float* w_qn   = (const float*)d_in[2];
    const float* w_kn   = (const float*)d_in[3];
    const float* W_wp   = (const float*)d_in[4];
    const float* b_wp   = (const float*)d_in[5];
    const float* w_on   = (const float*)d_in[6];
    const float* W_out  = (const float*)d_in[7];
    const float* W_gate = (const float*)d_in[8];
    const float* b_gate = (const float*)d_in[9];
    float* out = (float*)d_out;

    float* ws     = (float*)d_ws;
    float* qkv    = ws;                    // 8192*768
    float* qrot   = qkv  + 8192 * 768;     // 8192*256
    float* krot   = qrot + 8192 * 256;     // 8192*256
    float* attn_o = krot + 8192 * 256;     // 8192*256
    float* widthp = attn_o + 8192 * 256;   // 8192*4
    float* sharpp = widthp + 8192 * 4;     // 8192*4
    float* merged = qrot;                  // qrot dead after attn_kernel -> reuse

    // qkv = silu(x @ W_qkv)   (split-fp32 MFMA)
    gemm_mfma<0><<<dim3(6, 64), 256, 0, stream>>>(x, 256, W_qkv, 768, qkv, 768,
                                                  nullptr, nullptr, nullptr);
    // width / sharpness
    wp_kernel<<<256, 256, 0, stream>>>(x, W_wp, b_wp, widthp, sharpp);
    // q/k rmsnorm + rope
    normrope_kernel<<<8192, 256, 0, stream>>>(qkv, w_qn, w_kn, qrot, krot);
    // local attention + output rmsnorm
    attn_kernel<<<8192, 256, 0, stream>>>(qrot, krot, qkv, widthp, sharpp, w_on, attn_o);
    // gate gemm + merge
    gemm_mfma<1><<<dim3(2, 64), 256, 0, stream>>>(qkv + 512, 768, W_gate, 256, merged, 256,
                                                  b_gate, qkv + 512, attn_o);
    // final silu(merged @ W_out)
    gemm_mfma<0><<<dim3(2, 64), 256, 0, stream>>>(merged, 256, W_out, 256, out, 256,
                                                  nullptr, nullptr, nullptr);
}

// Round 5
// 180.844 us; speedup vs baseline: 2.6135x; 1.2211x over previous
//
#include <hip/hip_runtime.h>
#include <hip/hip_bf16.h>
#include <hip/hip_fp16.h>
#include <math.h>

__device__ __forceinline__ float sigm(float x)  { return 1.0f / (1.0f + __expf(-x)); }
__device__ __forceinline__ float siluf(float x) { return x * sigm(x); }

__device__ __forceinline__ float wredsum(float v) {
#pragma unroll
    for (int off = 32; off; off >>= 1) v += __shfl_xor(v, off);
    return v;
}

// ---- bf16 bit helpers (hi/lo split for fp32-accurate MFMA GEMMs) ----
__device__ __forceinline__ short f2bf(float f) {
    __hip_bfloat16 h = __float2bfloat16(f);
    return *reinterpret_cast<short*>(&h);
}
__device__ __forceinline__ float bf2f(short s) {
    __hip_bfloat16 h = *reinterpret_cast<__hip_bfloat16*>(&s);
    return __bfloat162float(h);
}
__device__ __forceinline__ int pack2(short a, short b) {
    return (int)((unsigned short)a | ((unsigned)(unsigned short)b << 16));
}

typedef short    bf16x8 __attribute__((ext_vector_type(8)));
typedef _Float16 half8  __attribute__((ext_vector_type(8)));
typedef _Float16 half4  __attribute__((ext_vector_type(4)));
typedef float    f32x4  __attribute__((ext_vector_type(4)));

// =======================================================================
// Split-fp32 MFMA GEMM (unchanged structure from R3).
// GATE=1 adds fused output-rmsnorm of obuf via sumsq4 + w_onorm.
// =======================================================================
template <int GATE>
__global__ __launch_bounds__(256, 2) void gemm_mfma(
    const float* __restrict__ A, int lda,
    const float* __restrict__ Bw, int ldb,
    float* __restrict__ Cc, int ldc,
    const float* __restrict__ bias,
    const float* __restrict__ vbuf,     // stride 768
    const float* __restrict__ obuf,     // stride 256 (raw attention out)
    const float* __restrict__ sumsq4,   // [M][4] per-head sumsq of obuf rows
    const float* __restrict__ w_onorm)
{
    __shared__ short AsHi[128 * 40], AsLo[128 * 40];
    __shared__ short BsHi[128 * 40], BsLo[128 * 40];   // [n][k] layout

    const int t    = threadIdx.x;
    const int m0   = blockIdx.y << 7, n0 = blockIdx.x << 7;
    const int lane = t & 63;
    const int wave = t >> 6;
    const int wm   = (wave >> 1) << 6, wn = (wave & 1) << 6;
    const int fr   = lane & 15;
    const int fq   = lane >> 4;

    f32x4 acc[4][4] = {};

    const int ar  = t >> 3, akc = (t & 7) << 2;
    const int bn  = t & 127, bkh = (t >> 7) << 4;

    for (int k0 = 0; k0 < 256; k0 += 32) {
        float4 av[4];
#pragma unroll
        for (int p = 0; p < 4; ++p)
            av[p] = *(const float4*)&A[(size_t)(m0 + (p << 5) + ar) * lda + k0 + akc];
        float bv[16];
#pragma unroll
        for (int i = 0; i < 16; ++i)
            bv[i] = Bw[(size_t)(k0 + bkh + i) * ldb + n0 + bn];

        __syncthreads();

#pragma unroll
        for (int p = 0; p < 4; ++p) {
            short4 hi, lo;
            hi.x = f2bf(av[p].x); lo.x = f2bf(av[p].x - bf2f(hi.x));
            hi.y = f2bf(av[p].y); lo.y = f2bf(av[p].y - bf2f(hi.y));
            hi.z = f2bf(av[p].z); lo.z = f2bf(av[p].z - bf2f(hi.z));
            hi.w = f2bf(av[p].w); lo.w = f2bf(av[p].w - bf2f(hi.w));
            const int off = ((p << 5) + ar) * 40 + akc;
            *(short4*)&AsHi[off] = hi;
            *(short4*)&AsLo[off] = lo;
        }
        {
            short sh2[16], sl[16];
#pragma unroll
            for (int i = 0; i < 16; ++i) {
                sh2[i] = f2bf(bv[i]);
                sl[i]  = f2bf(bv[i] - bf2f(sh2[i]));
            }
#pragma unroll
            for (int j = 0; j < 2; ++j) {
                int4 ph, pl;
                ph.x = pack2(sh2[8*j+0], sh2[8*j+1]); pl.x = pack2(sl[8*j+0], sl[8*j+1]);
                ph.y = pack2(sh2[8*j+2], sh2[8*j+3]); pl.y = pack2(sl[8*j+2], sl[8*j+3]);
                ph.z = pack2(sh2[8*j+4], sh2[8*j+5]); pl.z = pack2(sl[8*j+4], sl[8*j+5]);
                ph.w = pack2(sh2[8*j+6], sh2[8*j+7]); pl.w = pack2(sl[8*j+6], sl[8*j+7]);
                const int off = bn * 40 + bkh + (j << 3);
                *(int4*)&BsHi[off] = ph;
                *(int4*)&BsLo[off] = pl;
            }
        }
        __syncthreads();

        bf16x8 ah[4], al[4], bh[4], bl[4];
#pragma unroll
        for (int i = 0; i < 4; ++i) {
            const int aoff = (wm + (i << 4) + fr) * 40 + (fq << 3);
            ah[i] = *(const bf16x8*)&AsHi[aoff];
            al[i] = *(const bf16x8*)&AsLo[aoff];
            const int boff = (wn + (i << 4) + fr) * 40 + (fq << 3);
            bh[i] = *(const bf16x8*)&BsHi[boff];
            bl[i] = *(const bf16x8*)&BsLo[boff];
        }
#pragma unroll
        for (int mi = 0; mi < 4; ++mi)
#pragma unroll
            for (int ni = 0; ni < 4; ++ni) {
                acc[mi][ni] = __builtin_amdgcn_mfma_f32_16x16x32_bf16(ah[mi], bh[ni], acc[mi][ni], 0, 0, 0);
                acc[mi][ni] = __builtin_amdgcn_mfma_f32_16x16x32_bf16(al[mi], bh[ni], acc[mi][ni], 0, 0, 0);
                acc[mi][ni] = __builtin_amdgcn_mfma_f32_16x16x32_bf16(ah[mi], bl[ni], acc[mi][ni], 0, 0, 0);
            }
    }

    float rmsf[4][4];
    if (GATE) {
#pragma unroll
        for (int mi = 0; mi < 4; ++mi)
#pragma unroll
            for (int r = 0; r < 4; ++r) {
                const int m = m0 + wm + (mi << 4) + (fq << 2) + r;
                float4 s4 = *(const float4*)&sumsq4[(size_t)m * 4];
                rmsf[mi][r] = 1.f / sqrtf((s4.x + s4.y + s4.z + s4.w) * (1.f / 256.f) + 1e-6f);
            }
    }

#pragma unroll
    for (int mi = 0; mi < 4; ++mi)
#pragma unroll
        for (int ni = 0; ni < 4; ++ni) {
            const int n  = n0 + wn + (ni << 4) + fr;
            const int mb = m0 + wm + (mi << 4) + (fq << 2);
            if (GATE) {
                const float bb  = bias[n];
                const float won = w_onorm[n];
#pragma unroll
                for (int r = 0; r < 4; ++r) {
                    const int m = mb + r;
                    const float g  = sigm(siluf(acc[mi][ni][r] + bb));
                    const float vv = vbuf[(size_t)m * 768 + n];
                    const float oo = obuf[(size_t)m * 256 + n] * rmsf[mi][r] * won;
                    Cc[(size_t)m * ldc + n] = g * vv + (1.f - g) * oo;
                }
            } else {
#pragma unroll
                for (int r = 0; r < 4; ++r) {
                    const int m = mb + r;
                    Cc[(size_t)m * ldc + n] = siluf(acc[mi][ni][r]);
                }
            }
        }
}

// ---------------- wp = silu(x@W_wp + b_wp) -> width/sharp ----------------
__global__ __launch_bounds__(256) void wp_kernel(
    const float* __restrict__ x, const float* __restrict__ Wwp,
    const float* __restrict__ bwp, float* __restrict__ width,
    float* __restrict__ sharp)
{
    __shared__ float xs[32][260];
    const int t = threadIdx.x;
    const int row0 = blockIdx.x << 5;
    for (int e = t; e < 2048; e += 256) {
        int r = e >> 6, cc = (e & 63) << 2;
        *(float4*)&xs[r][cc] = *(const float4*)&x[(row0 + r) * 256 + cc];
    }
    __syncthreads();
    const int rl = t >> 3, n = t & 7;
    float acc = 0.f;
#pragma unroll 8
    for (int k = 0; k < 256; ++k) acc += xs[rl][k] * Wwp[k * 8 + n];
    float s = sigm(siluf(acc + bwp[n]));
    const int row = row0 + rl;
    if (n < 4) width[row * 4 + n] = s * 4.242640687119285f + 0.5f;  // sqrt(18)
    else       sharp[row * 4 + n - 4] = s * 9.5f + 0.5f;
}

// -------- rmsnorm(D=64) + RoPE (pos = head index) -> fp16 q,k; fp16 v passthrough -----
__global__ __launch_bounds__(256) void normrope_kernel(
    const float* __restrict__ qkv, const float* __restrict__ wq,
    const float* __restrict__ wk, __half* __restrict__ qh,
    __half* __restrict__ kh, __half* __restrict__ vh)
{
    const int row = blockIdx.x;
    const int h = threadIdx.x >> 6, lane = threadIdx.x & 63;
    const int idx = lane & 31;
    const float freq = powf(10000.f, -(float)idx * (1.f / 32.f));
    const float ang = (float)h * freq;        // pos = arange(H) in the reference
    const float cs = cosf(ang), sn = sinf(ang);
#pragma unroll
    for (int which = 0; which < 2; ++which) {
        const float* src = qkv + row * 768 + which * 256 + h * 64 + lane;
        const float* w = which ? wk : wq;
        float v = *src;
        float ss = wredsum(v * v);
        float rms = sqrtf(ss * (1.f / 64.f) + 1e-6f);
        float val = v / rms * w[lane];
        float partner = __shfl_xor(val, 32);
        float outv = (lane < 32) ? (val * cs - partner * sn)
                                 : (partner * sn + val * cs);
        __half* dst = (which ? kh : qh) + row * 256 + h * 64 + lane;
        *dst = __float2half(outv);
    }
    const float v = qkv[row * 768 + 512 + h * 64 + lane];
    vh[row * 256 + h * 64 + lane] = __float2half(v);
}

// =======================================================================
// Patch-GEMM local attention. Block = (8x8 query patch, head, batch).
// Union of windows = 14x14 = 196 positions; S[64q x 208p] = Q K^T (MFMA),
// soft-mask + window mask + softmax in regs, P->LDS (C->A layout), PV (MFMA).
// LDS 63.5 KB -> 2 blocks/CU; 512 blocks co-resident in one round.
// =======================================================================
#define PT 216   // P / Vt row stride (halves); mult of 8, 2-way banks

__global__ __launch_bounds__(256, 2) void attn_mfma(
    const __half* __restrict__ qh, const __half* __restrict__ kh,
    const __half* __restrict__ vh, const float* __restrict__ width,
    const float* __restrict__ sharp, float* __restrict__ attn_o,
    float* __restrict__ sumsq4)
{
    __shared__ short smem[31744];          // 63488 B
    short* Ksh = smem;                     // [208 rows][64] chunk-swizzled; overlaid by P [64][PT]
    short* Psh = smem;
    short* Vt  = smem + 13824;             // [64 d][PT]
    short* Qsh = smem + 27648;             // [64 q][64] chunk-swizzled

    const int t = threadIdx.x;
    const int lane = t & 63, wave = t >> 6;
    const int fr = lane & 15, fq = lane >> 4;
    const int patch = blockIdx.x, h = blockIdx.y, b = blockIdx.z;
    const int pr0 = (patch >> 3) << 3, pc0 = (patch & 7) << 3;

    // per-lane query meta: q = wave*16 + fq*4 + r  (C/D row layout)
    float wd[4], sh[4]; int lq[4];
#pragma unroll
    for (int r = 0; r < 4; ++r) {
        const int q = (wave << 4) + (fq << 2) + r;
        lq[r] = (pr0 + (q >> 3)) * 64 + pc0 + (q & 7);
        wd[r] = width[((b << 12) + lq[r]) * 4 + h];
        sh[r] = sharp[((b << 12) + lq[r]) * 4 + h];
    }

    // ---- staging: all global loads issued as clamped+select (R2 lesson) ----
    const int srow = t >> 5;              // 8 rows per pass
    const int d2 = (t & 31) << 1;         // even channel within head
    const size_t cbase = (((size_t)b << 12) * 256) + (size_t)h * 64 + d2;

    unsigned kb[25], vb[25];
#pragma unroll
    for (int p5 = 0; p5 < 25; ++p5) {
        const int prow = p5 * 8 + srow;                 // 0..199
        const int pi = prow / 14, pj = prow - pi * 14;
        const int gr = pr0 - 3 + pi, gc = pc0 - 3 + pj;
        const bool ok = (prow < 196) & ((unsigned)gr < 64u) & ((unsigned)gc < 64u);
        const int grc = min(max(gr, 0), 63), gcc = min(max(gc, 0), 63);
        const size_t off = cbase + (size_t)(grc * 64 + gcc) * 256;
        unsigned kv = *(const unsigned*)(kh + off);
        unsigned vv = *(const unsigned*)(vh + off);
        kb[p5] = ok ? kv : 0u;
        vb[p5] = ok ? vv : 0u;
    }
    unsigned qb[8];
#pragma unroll
    for (int p5 = 0; p5 < 8; ++p5) {
        const int q = p5 * 8 + srow;
        const int l = (pr0 + (q >> 3)) * 64 + pc0 + (q & 7);
        qb[p5] = *(const unsigned*)(qh + cbase + (size_t)l * 256);
    }

    const int chunk = d2 >> 3, dlo = d2 & 7;
#pragma unroll
    for (int p5 = 0; p5 < 25; ++p5) {
        const int prow = p5 * 8 + srow;                 // rows 196..199 get zeros
        *(unsigned*)&Ksh[(prow << 6) + ((chunk ^ (prow & 7)) << 3) + dlo] = kb[p5];
        Vt[(d2)     * PT + prow] = (short)(vb[p5] & 0xffffu);
        Vt[(d2 + 1) * PT + prow] = (short)(vb[p5] >> 16);
    }
#pragma unroll
    for (int p5 = 0; p5 < 8; ++p5) {
        const int q = p5 * 8 + srow;
        *(unsigned*)&Qsh[(q << 6) + ((chunk ^ (q & 7)) << 3) + dlo] = qb[p5];
    }
    // zero Vt pad cols 196..215 (PV contracts k<208; garbage*0 could NaN)
    for (int i = t; i < 64 * 20; i += 256)
        Vt[(i / 20) * PT + 196 + (i % 20)] = 0;
    __syncthreads();

    // ---- QK^T: 13 n-tiles of 16 positions ----
    const int qrow = (wave << 4) + fr;
    half8 a0 = *(const half8*)&Qsh[(qrow << 6) + (((0 + fq) ^ (qrow & 7)) << 3)];
    half8 a1 = *(const half8*)&Qsh[(qrow << 6) + (((4 + fq) ^ (qrow & 7)) << 3)];
    f32x4 sc[13];
#pragma unroll
    for (int tl = 0; tl < 13; ++tl) {
        const int kr = (tl << 4) + fr;
        half8 b0 = *(const half8*)&Ksh[(kr << 6) + (((0 + fq) ^ (kr & 7)) << 3)];
        half8 b1 = *(const half8*)&Ksh[(kr << 6) + (((4 + fq) ^ (kr & 7)) << 3)];
        f32x4 z = {0.f, 0.f, 0.f, 0.f};
        z = __builtin_amdgcn_mfma_f32_16x16x32_f16(a0, b0, z, 0, 0, 0);
        sc[tl] = __builtin_amdgcn_mfma_f32_16x16x32_f16(a1, b1, z, 0, 0, 0);
    }

    // ---- mask + softmax (rows q = fq*4+r live across fr-lanes 0..15) ----
    float mx[4] = {-3e38f, -3e38f, -3e38f, -3e38f};
#pragma unroll
    for (int tl = 0; tl < 13; ++tl) {
        const int p = (tl << 4) + fr;
        const int pi = p / 14, pj = p - pi * 14;
        const bool pvld = p < 196;
#pragma unroll
        for (int r = 0; r < 4; ++r) {
            const int q = (wave << 4) + (fq << 2) + r;
            const int di = pi - 3 - ((q >> 3) & 7), dj = pj - 3 - (q & 7);
            const bool win = pvld & ((unsigned)(di + 3) <= 6u) & ((unsigned)(dj + 3) <= 6u);
            const float rel = sqrtf((float)(di * di + dj * dj));
            const float mk = sigm((wd[r] - rel) * sh[r]);
            float s = sc[tl][r] * 0.125f - (1.f - mk) * 10000.f;
            s = win ? s : -3e38f;              // cndmask kills any NaN from garbage K rows
            sc[tl][r] = s;
            mx[r] = fmaxf(mx[r], s);
        }
    }
#pragma unroll
    for (int r = 0; r < 4; ++r) {
        mx[r] = fmaxf(mx[r], __shfl_xor(mx[r], 1));
        mx[r] = fmaxf(mx[r], __shfl_xor(mx[r], 2));
        mx[r] = fmaxf(mx[r], __shfl_xor(mx[r], 4));
        mx[r] = fmaxf(mx[r], __shfl_xor(mx[r], 8));
    }
    float sm[4] = {0.f, 0.f, 0.f, 0.f};
#pragma unroll
    for (int tl = 0; tl < 13; ++tl)
#pragma unroll
        for (int r = 0; r < 4; ++r) {
            const float e = __expf(sc[tl][r] - mx[r]);   // masked -> exp(-huge) = 0
            sc[tl][r] = e; sm[r] += e;
        }
#pragma unroll
    for (int r = 0; r < 4; ++r) {
        sm[r] += __shfl_xor(sm[r], 1);
        sm[r] += __shfl_xor(sm[r], 2);
        sm[r] += __shfl_xor(sm[r], 4);
        sm[r] += __shfl_xor(sm[r], 8);
        sm[r] = 1.f / sm[r];
    }

    __syncthreads();   // all Ksh frag reads done before P overwrites the region
#pragma unroll
    for (int tl = 0; tl < 13; ++tl)
#pragma unroll
        for (int r = 0; r < 4; ++r) {
            __half pv = __float2half(sc[tl][r] * sm[r]);
            Psh[((wave << 4) + (fq << 2) + r) * PT + (tl << 4) + fr] = *(short*)&pv;
        }
    __syncthreads();

    // ---- PV: O[16q x 64d] per wave; K = 192 (6x32) + 16 (16x16x16) ----
    f32x4 o[4] = {};
    const int pra = (wave << 4) + fr;      // A row = q (A layout m = lane&15)
#pragma unroll
    for (int s = 0; s < 6; ++s) {
        half8 pa = *(const half8*)&Psh[pra * PT + (fq << 3) + (s << 5)];
#pragma unroll
        for (int dt = 0; dt < 4; ++dt) {
            half8 vbf = *(const half8*)&Vt[((dt << 4) + fr) * PT + (fq << 3) + (s << 5)];
            o[dt] = __builtin_amdgcn_mfma_f32_16x16x32_f16(pa, vbf, o[dt], 0, 0, 0);
        }
    }
    {
        half4 pa = *(const half4*)&Psh[pra * PT + 192 + (fq << 2)];
#pragma unroll
        for (int dt = 0; dt < 4; ++dt) {
            half4 vbf = *(const half4*)&Vt[((dt << 4) + fr) * PT + 192 + (fq << 2)];
            o[dt] = __builtin_amdgcn_mfma_f32_16x16x16f16(pa, vbf, o[dt], 0, 0, 0);
        }
    }

    // ---- write raw O + per-(q,h) sumsq (rmsnorm folded into gate epilogue) ----
#pragma unroll
    for (int r = 0; r < 4; ++r) {
        float ss = o[0][r]*o[0][r] + o[1][r]*o[1][r] + o[2][r]*o[2][r] + o[3][r]*o[3][r];
        ss += __shfl_xor(ss, 1); ss += __shfl_xor(ss, 2);
        ss += __shfl_xor(ss, 4); ss += __shfl_xor(ss, 8);
        const size_t rowb = (((size_t)(b << 12) + lq[r]) << 8) + h * 64;
#pragma unroll
        for (int dt = 0; dt < 4; ++dt)
            attn_o[rowb + (dt << 4) + fr] = o[dt][r];
        if (fr == 0) sumsq4[(((b << 12) + lq[r]) << 2) + h] = ss;
    }
}

extern "C" void kernel_launch(void* const* d_in, const int* in_sizes, int n_in,
                              void* d_out, int out_size, void* d_ws, size_t ws_size,
                              hipStream_t stream)
{
    const float* x      = (const float*)d_in[0];
    const float* W_qkv  = (const float*)d_in[1];
    const float* w_qn   = (const float*)d_in[2];
    const float* w_kn   = (const float*)d_in[3];
    const float* W_wp   = (const float*)d_in[4];
    const float* b_wp   = (const float*)d_in[5];
    const float* w_on   = (const float*)d_in[6];
    const float* W_out  = (const float*)d_in[7];
    const float* W_gate = (const float*)d_in[8];
    const float* b_gate = (const float*)d_in[9];
    float* out = (float*)d_out;

    float*  qkv    = (float*)d_ws;                  // 8192*768 f32
    __half* qhp    = (__half*)(qkv + 8192 * 768);   // 8192*256 f16
    __half* khp    = qhp + 8192 * 256;
    __half* vhp    = khp + 8192 * 256;
    float*  attn_o = (float*)(vhp + 8192 * 256);    // 8192*256 f32
    float*  widthp = attn_o + 8192 * 256;
    float*  sharpp = widthp + 8192 * 4;
    float*  sumsq4 = sharpp + 8192 * 4;             // 8192*4
    float*  merged = (float*)qhp;                   // qh/kh dead after attn -> reuse 8MB

    // qkv = silu(x @ W_qkv)
    gemm_mfma<0><<<dim3(6, 64), 256, 0, stream>>>(x, 256, W_qkv, 768, qkv, 768,
                                                  nullptr, nullptr, nullptr, nullptr, nullptr);
    // width / sharpness
    wp_kernel<<<256, 256, 0, stream>>>(x, W_wp, b_wp, widthp, sharpp);
    // q/k rmsnorm + rope -> fp16; v -> fp16
    normrope_kernel<<<8192, 256, 0, stream>>>(qkv, w_qn, w_kn, qhp, khp, vhp);
    // patch-GEMM local attention (raw O + sumsq)
    attn_mfma<<<dim3(64, 4, 2), 256, 0, stream>>>(qhp, khp, vhp, widthp, sharpp,
                                                  attn_o, sumsq4);
    // gate gemm + fused o-rmsnorm + merge
    gemm_mfma<1><<<dim3(2, 64), 256, 0, stream>>>(qkv + 512, 768, W_gate, 256, merged, 256,
                                                  b_gate, qkv + 512, attn_o, sumsq4, w_on);
    // final silu(merged @ W_out)
    gemm_mfma<0><<<dim3(2, 64), 256, 0, stream>>>(merged, 256, W_out, 256, out, 256,
                                                  nullptr, nullptr, nullptr, nullptr, nullptr);
}

// Round 6
// 175.408 us; speedup vs baseline: 2.6944x; 1.0310x over previous
//
#include <hip/hip_runtime.h>
#include <hip/hip_bf16.h>
#include <hip/hip_fp16.h>
#include <math.h>

__device__ __forceinline__ float sigm(float x)  { return 1.0f / (1.0f + __expf(-x)); }
__device__ __forceinline__ float siluf(float x) { return x * sigm(x); }

// ---- bf16 bit helpers (hi/lo split for fp32-accurate MFMA GEMMs) ----
__device__ __forceinline__ short f2bf(float f) {
    __hip_bfloat16 h = __float2bfloat16(f);
    return *reinterpret_cast<short*>(&h);
}
__device__ __forceinline__ float bf2f(short s) {
    __hip_bfloat16 h = *reinterpret_cast<__hip_bfloat16*>(&s);
    return __bfloat162float(h);
}
__device__ __forceinline__ int pack2(short a, short b) {
    return (int)((unsigned short)a | ((unsigned)(unsigned short)b << 16));
}

typedef short    bf16x8 __attribute__((ext_vector_type(8)));
typedef _Float16 half8  __attribute__((ext_vector_type(8)));
typedef _Float16 half4  __attribute__((ext_vector_type(4)));
typedef float    f32x4  __attribute__((ext_vector_type(4)));

// =======================================================================
// Shared split-fp32 MFMA GEMM core: acc = A[128xK] @ B[Kx128] for this block,
// K=256.  x = hi + lo (bf16 each); x*w ~ hi*hi + lo*hi + hi*lo.
// =======================================================================
__device__ __forceinline__ void gemm_core(
    const float* __restrict__ A, int lda,
    const float* __restrict__ Bw, int ldb,
    int m0, int n0, int t, f32x4 (&acc)[4][4])
{
    __shared__ short AsHi[128 * 40], AsLo[128 * 40];
    __shared__ short BsHi[128 * 40], BsLo[128 * 40];   // [n][k] layout

    const int lane = t & 63;
    const int wave = t >> 6;
    const int wm   = (wave >> 1) << 6, wn = (wave & 1) << 6;
    const int fr   = lane & 15;
    const int fq   = lane >> 4;

    const int ar  = t >> 3, akc = (t & 7) << 2;
    const int bn  = t & 127, bkh = (t >> 7) << 4;

    for (int k0 = 0; k0 < 256; k0 += 32) {
        float4 av[4];
#pragma unroll
        for (int p = 0; p < 4; ++p)
            av[p] = *(const float4*)&A[(size_t)(m0 + (p << 5) + ar) * lda + k0 + akc];
        float bv[16];
#pragma unroll
        for (int i = 0; i < 16; ++i)
            bv[i] = Bw[(size_t)(k0 + bkh + i) * ldb + n0 + bn];

        __syncthreads();

#pragma unroll
        for (int p = 0; p < 4; ++p) {
            short4 hi, lo;
            hi.x = f2bf(av[p].x); lo.x = f2bf(av[p].x - bf2f(hi.x));
            hi.y = f2bf(av[p].y); lo.y = f2bf(av[p].y - bf2f(hi.y));
            hi.z = f2bf(av[p].z); lo.z = f2bf(av[p].z - bf2f(hi.z));
            hi.w = f2bf(av[p].w); lo.w = f2bf(av[p].w - bf2f(hi.w));
            const int off = ((p << 5) + ar) * 40 + akc;
            *(short4*)&AsHi[off] = hi;
            *(short4*)&AsLo[off] = lo;
        }
        {
            short sh2[16], sl[16];
#pragma unroll
            for (int i = 0; i < 16; ++i) {
                sh2[i] = f2bf(bv[i]);
                sl[i]  = f2bf(bv[i] - bf2f(sh2[i]));
            }
#pragma unroll
            for (int j = 0; j < 2; ++j) {
                int4 ph, pl;
                ph.x = pack2(sh2[8*j+0], sh2[8*j+1]); pl.x = pack2(sl[8*j+0], sl[8*j+1]);
                ph.y = pack2(sh2[8*j+2], sh2[8*j+3]); pl.y = pack2(sl[8*j+2], sl[8*j+3]);
                ph.z = pack2(sh2[8*j+4], sh2[8*j+5]); pl.z = pack2(sl[8*j+4], sl[8*j+5]);
                ph.w = pack2(sh2[8*j+6], sh2[8*j+7]); pl.w = pack2(sl[8*j+6], sl[8*j+7]);
                const int off = bn * 40 + bkh + (j << 3);
                *(int4*)&BsHi[off] = ph;
                *(int4*)&BsLo[off] = pl;
            }
        }
        __syncthreads();

        bf16x8 ah[4], al[4], bh[4], bl[4];
#pragma unroll
        for (int i = 0; i < 4; ++i) {
            const int aoff = (wm + (i << 4) + fr) * 40 + (fq << 3);
            ah[i] = *(const bf16x8*)&AsHi[aoff];
            al[i] = *(const bf16x8*)&AsLo[aoff];
            const int boff = (wn + (i << 4) + fr) * 40 + (fq << 3);
            bh[i] = *(const bf16x8*)&BsHi[boff];
            bl[i] = *(const bf16x8*)&BsLo[boff];
        }
#pragma unroll
        for (int mi = 0; mi < 4; ++mi)
#pragma unroll
            for (int ni = 0; ni < 4; ++ni) {
                acc[mi][ni] = __builtin_amdgcn_mfma_f32_16x16x32_bf16(ah[mi], bh[ni], acc[mi][ni], 0, 0, 0);
                acc[mi][ni] = __builtin_amdgcn_mfma_f32_16x16x32_bf16(al[mi], bh[ni], acc[mi][ni], 0, 0, 0);
                acc[mi][ni] = __builtin_amdgcn_mfma_f32_16x16x32_bf16(ah[mi], bl[ni], acc[mi][ni], 0, 0, 0);
            }
    }
}

// =======================================================================
// qkv GEMM with FUSED silu -> rmsnorm(D=64) -> RoPE(pos=head) -> fp16 store.
// A wave's 64 output cols = exactly one (segment, head): rmsnorm is a
// lane-local 4-sum + shfl over fr lanes; RoPE pairs (ni, ni+2) lane-locally.
// Writes: q,k fp16 (rotated); v fp16 + fp32. No fp32 qkv intermediate.
// =======================================================================
__global__ __launch_bounds__(256, 2) void gemm_qkv(
    const float* __restrict__ x, const float* __restrict__ Wqkv,
    const float* __restrict__ wq, const float* __restrict__ wk,
    __half* __restrict__ qh, __half* __restrict__ kh,
    __half* __restrict__ vh, float* __restrict__ v32)
{
    const int t  = threadIdx.x;
    const int m0 = blockIdx.y << 7, n0 = blockIdx.x << 7;
    f32x4 acc[4][4] = {};
    gemm_core(x, 256, Wqkv, 768, m0, n0, t, acc);

    const int lane = t & 63, wave = t >> 6;
    const int wm = (wave >> 1) << 6, wn = (wave & 1) << 6;
    const int fr = lane & 15, fq = lane >> 4;
    const int gc0 = n0 + wn;          // wave's first global col (multiple of 64)
    const int seg = gc0 >> 8;         // 0=q, 1=k, 2=v
    const int h   = (gc0 >> 6) & 3;   // head
    const int hc0 = h << 6;           // col base within 256-wide channel dim

    // silu on everything first (reference: qkv = silu(x@W) before split)
#pragma unroll
    for (int mi = 0; mi < 4; ++mi)
#pragma unroll
        for (int ni = 0; ni < 4; ++ni)
#pragma unroll
            for (int r = 0; r < 4; ++r)
                acc[mi][ni][r] = siluf(acc[mi][ni][r]);

    if (seg == 2) {
#pragma unroll
        for (int mi = 0; mi < 4; ++mi)
#pragma unroll
            for (int r = 0; r < 4; ++r) {
                const size_t row = m0 + wm + (mi << 4) + (fq << 2) + r;
#pragma unroll
                for (int ni = 0; ni < 4; ++ni) {
                    const int c = hc0 + (ni << 4) + fr;
                    v32[row * 256 + c] = acc[mi][ni][r];
                    vh[row * 256 + c]  = __float2half(acc[mi][ni][r]);
                }
            }
    } else {
        const float* wnorm = seg ? wk : wq;
        float wv[4];
#pragma unroll
        for (int ni = 0; ni < 4; ++ni) wv[ni] = wnorm[(ni << 4) + fr];
        // RoPE angles: pair j pairs d=j*16+fr with d+32; pos = h (reference quirk)
        float cs[2], sn[2];
#pragma unroll
        for (int j = 0; j < 2; ++j) {
            const int d = (j << 4) + fr;
            const float freq = powf(10000.f, -(float)d * (1.f / 32.f));
            const float ang = (float)h * freq;
            cs[j] = cosf(ang); sn[j] = sinf(ang);
        }
        __half* dstbase = (seg ? kh : qh);
#pragma unroll
        for (int mi = 0; mi < 4; ++mi)
#pragma unroll
            for (int r = 0; r < 4; ++r) {
                float ss = acc[mi][0][r] * acc[mi][0][r] + acc[mi][1][r] * acc[mi][1][r]
                         + acc[mi][2][r] * acc[mi][2][r] + acc[mi][3][r] * acc[mi][3][r];
                ss += __shfl_xor(ss, 1); ss += __shfl_xor(ss, 2);
                ss += __shfl_xor(ss, 4); ss += __shfl_xor(ss, 8);
                const float rinv = 1.f / sqrtf(ss * (1.f / 64.f) + 1e-6f);
                float xv[4];
#pragma unroll
                for (int ni = 0; ni < 4; ++ni) xv[ni] = acc[mi][ni][r] * rinv * wv[ni];
                const float o0 = xv[0] * cs[0] - xv[2] * sn[0];
                const float o2 = xv[0] * sn[0] + xv[2] * cs[0];
                const float o1 = xv[1] * cs[1] - xv[3] * sn[1];
                const float o3 = xv[1] * sn[1] + xv[3] * cs[1];
                const size_t row = m0 + wm + (mi << 4) + (fq << 2) + r;
                __half* dst = dstbase + row * 256 + hc0;
                dst[fr]      = __float2half(o0);
                dst[16 + fr] = __float2half(o1);
                dst[32 + fr] = __float2half(o2);
                dst[48 + fr] = __float2half(o3);
            }
    }
}

// =======================================================================
// Generic GEMM.  GATE=0: C = silu(A@B).
// GATE=1: g = sigmoid(silu(A@B+bias)); C = g*v + (1-g)*rmsnorm(o)*w_onorm
// =======================================================================
template <int GATE>
__global__ __launch_bounds__(256, 2) void gemm_mfma(
    const float* __restrict__ A, int lda,
    const float* __restrict__ Bw, int ldb,
    float* __restrict__ Cc, int ldc,
    const float* __restrict__ bias,
    const float* __restrict__ vbuf, int ldv,
    const float* __restrict__ obuf,
    const float* __restrict__ sumsq4,
    const float* __restrict__ w_onorm)
{
    const int t  = threadIdx.x;
    const int m0 = blockIdx.y << 7, n0 = blockIdx.x << 7;
    f32x4 acc[4][4] = {};
    gemm_core(A, lda, Bw, ldb, m0, n0, t, acc);

    const int lane = t & 63, wave = t >> 6;
    const int wm = (wave >> 1) << 6, wn = (wave & 1) << 6;
    const int fr = lane & 15, fq = lane >> 4;

    float rmsf[4][4];
    if (GATE) {
#pragma unroll
        for (int mi = 0; mi < 4; ++mi)
#pragma unroll
            for (int r = 0; r < 4; ++r) {
                const int m = m0 + wm + (mi << 4) + (fq << 2) + r;
                float4 s4 = *(const float4*)&sumsq4[(size_t)m * 4];
                rmsf[mi][r] = 1.f / sqrtf((s4.x + s4.y + s4.z + s4.w) * (1.f / 256.f) + 1e-6f);
            }
    }

#pragma unroll
    for (int mi = 0; mi < 4; ++mi)
#pragma unroll
        for (int ni = 0; ni < 4; ++ni) {
            const int n  = n0 + wn + (ni << 4) + fr;
            const int mb = m0 + wm + (mi << 4) + (fq << 2);
            if (GATE) {
                const float bb  = bias[n];
                const float won = w_onorm[n];
#pragma unroll
                for (int r = 0; r < 4; ++r) {
                    const int m = mb + r;
                    const float g  = sigm(siluf(acc[mi][ni][r] + bb));
                    const float vv = vbuf[(size_t)m * ldv + n];
                    const float oo = obuf[(size_t)m * 256 + n] * rmsf[mi][r] * won;
                    Cc[(size_t)m * ldc + n] = g * vv + (1.f - g) * oo;
                }
            } else {
#pragma unroll
                for (int r = 0; r < 4; ++r) {
                    const int m = mb + r;
                    Cc[(size_t)m * ldc + n] = siluf(acc[mi][ni][r]);
                }
            }
        }
}

// ---------------- wp = silu(x@W_wp + b_wp) -> width/sharp ----------------
__global__ __launch_bounds__(256) void wp_kernel(
    const float* __restrict__ x, const float* __restrict__ Wwp,
    const float* __restrict__ bwp, float* __restrict__ width,
    float* __restrict__ sharp)
{
    __shared__ float xs[32][260];
    const int t = threadIdx.x;
    const int row0 = blockIdx.x << 5;
    for (int e = t; e < 2048; e += 256) {
        int r = e >> 6, cc = (e & 63) << 2;
        *(float4*)&xs[r][cc] = *(const float4*)&x[(row0 + r) * 256 + cc];
    }
    __syncthreads();
    const int rl = t >> 3, n = t & 7;
    float acc = 0.f;
#pragma unroll 8
    for (int k = 0; k < 256; ++k) acc += xs[rl][k] * Wwp[k * 8 + n];
    float s = sigm(siluf(acc + bwp[n]));
    const int row = row0 + rl;
    if (n < 4) width[row * 4 + n] = s * 4.242640687119285f + 0.5f;  // sqrt(18)
    else       sharp[row * 4 + n - 4] = s * 9.5f + 0.5f;
}

// =======================================================================
// Patch-GEMM local attention (unchanged from R5).
// =======================================================================
#define PT 216   // P / Vt row stride (halves)

__global__ __launch_bounds__(256, 2) void attn_mfma(
    const __half* __restrict__ qh, const __half* __restrict__ kh,
    const __half* __restrict__ vh, const float* __restrict__ width,
    const float* __restrict__ sharp, float* __restrict__ attn_o,
    float* __restrict__ sumsq4)
{
    __shared__ short smem[31744];          // 63488 B
    short* Ksh = smem;                     // [208 rows][64] chunk-swizzled; overlaid by P
    short* Psh = smem;
    short* Vt  = smem + 13824;             // [64 d][PT]
    short* Qsh = smem + 27648;             // [64 q][64] chunk-swizzled

    const int t = threadIdx.x;
    const int lane = t & 63, wave = t >> 6;
    const int fr = lane & 15, fq = lane >> 4;
    const int patch = blockIdx.x, h = blockIdx.y, b = blockIdx.z;
    const int pr0 = (patch >> 3) << 3, pc0 = (patch & 7) << 3;

    float wd[4], sh[4]; int lq[4];
#pragma unroll
    for (int r = 0; r < 4; ++r) {
        const int q = (wave << 4) + (fq << 2) + r;
        lq[r] = (pr0 + (q >> 3)) * 64 + pc0 + (q & 7);
        wd[r] = width[((b << 12) + lq[r]) * 4 + h];
        sh[r] = sharp[((b << 12) + lq[r]) * 4 + h];
    }

    const int srow = t >> 5;
    const int d2 = (t & 31) << 1;
    const size_t cbase = (((size_t)b << 12) * 256) + (size_t)h * 64 + d2;

    unsigned kb[25], vb[25];
#pragma unroll
    for (int p5 = 0; p5 < 25; ++p5) {
        const int prow = p5 * 8 + srow;
        const int pi = prow / 14, pj = prow - pi * 14;
        const int gr = pr0 - 3 + pi, gc = pc0 - 3 + pj;
        const bool ok = (prow < 196) & ((unsigned)gr < 64u) & ((unsigned)gc < 64u);
        const int grc = min(max(gr, 0), 63), gcc = min(max(gc, 0), 63);
        const size_t off = cbase + (size_t)(grc * 64 + gcc) * 256;
        unsigned kv = *(const unsigned*)(kh + off);
        unsigned vv = *(const unsigned*)(vh + off);
        kb[p5] = ok ? kv : 0u;
        vb[p5] = ok ? vv : 0u;
    }
    unsigned qb[8];
#pragma unroll
    for (int p5 = 0; p5 < 8; ++p5) {
        const int q = p5 * 8 + srow;
        const int l = (pr0 + (q >> 3)) * 64 + pc0 + (q & 7);
        qb[p5] = *(const unsigned*)(qh + cbase + (size_t)l * 256);
    }

    const int chunk = d2 >> 3, dlo = d2 & 7;
#pragma unroll
    for (int p5 = 0; p5 < 25; ++p5) {
        const int prow = p5 * 8 + srow;
        *(unsigned*)&Ksh[(prow << 6) + ((chunk ^ (prow & 7)) << 3) + dlo] = kb[p5];
        Vt[(d2)     * PT + prow] = (short)(vb[p5] & 0xffffu);
        Vt[(d2 + 1) * PT + prow] = (short)(vb[p5] >> 16);
    }
#pragma unroll
    for (int p5 = 0; p5 < 8; ++p5) {
        const int q = p5 * 8 + srow;
        *(unsigned*)&Qsh[(q << 6) + ((chunk ^ (q & 7)) << 3) + dlo] = qb[p5];
    }
    for (int i = t; i < 64 * 20; i += 256)
        Vt[(i / 20) * PT + 196 + (i % 20)] = 0;
    __syncthreads();

    const int qrow = (wave << 4) + fr;
    half8 a0 = *(const half8*)&Qsh[(qrow << 6) + (((0 + fq) ^ (qrow & 7)) << 3)];
    half8 a1 = *(const half8*)&Qsh[(qrow << 6) + (((4 + fq) ^ (qrow & 7)) << 3)];
    f32x4 sc[13];
#pragma unroll
    for (int tl = 0; tl < 13; ++tl) {
        const int kr = (tl << 4) + fr;
        half8 b0 = *(const half8*)&Ksh[(kr << 6) + (((0 + fq) ^ (kr & 7)) << 3)];
        half8 b1 = *(const half8*)&Ksh[(kr << 6) + (((4 + fq) ^ (kr & 7)) << 3)];
        f32x4 z = {0.f, 0.f, 0.f, 0.f};
        z = __builtin_amdgcn_mfma_f32_16x16x32_f16(a0, b0, z, 0, 0, 0);
        sc[tl] = __builtin_amdgcn_mfma_f32_16x16x32_f16(a1, b1, z, 0, 0, 0);
    }

    float mx[4] = {-3e38f, -3e38f, -3e38f, -3e38f};
#pragma unroll
    for (int tl = 0; tl < 13; ++tl) {
        const int p = (tl << 4) + fr;
        const int pi = p / 14, pj = p - pi * 14;
        const bool pvld = p < 196;
#pragma unroll
        for (int r = 0; r < 4; ++r) {
            const int q = (wave << 4) + (fq << 2) + r;
            const int di = pi - 3 - ((q >> 3) & 7), dj = pj - 3 - (q & 7);
            const bool win = pvld & ((unsigned)(di + 3) <= 6u) & ((unsigned)(dj + 3) <= 6u);
            const float rel = sqrtf((float)(di * di + dj * dj));
            const float mk = sigm((wd[r] - rel) * sh[r]);
            float s = sc[tl][r] * 0.125f - (1.f - mk) * 10000.f;
            s = win ? s : -3e38f;
            sc[tl][r] = s;
            mx[r] = fmaxf(mx[r], s);
        }
    }
#pragma unroll
    for (int r = 0; r < 4; ++r) {
        mx[r] = fmaxf(mx[r], __shfl_xor(mx[r], 1));
        mx[r] = fmaxf(mx[r], __shfl_xor(mx[r], 2));
        mx[r] = fmaxf(mx[r], __shfl_xor(mx[r], 4));
        mx[r] = fmaxf(mx[r], __shfl_xor(mx[r], 8));
    }
    float sm[4] = {0.f, 0.f, 0.f, 0.f};
#pragma unroll
    for (int tl = 0; tl < 13; ++tl)
#pragma unroll
        for (int r = 0; r < 4; ++r) {
            const float e = __expf(sc[tl][r] - mx[r]);
            sc[tl][r] = e; sm[r] += e;
        }
#pragma unroll
    for (int r = 0; r < 4; ++r) {
        sm[r] += __shfl_xor(sm[r], 1);
        sm[r] += __shfl_xor(sm[r], 2);
        sm[r] += __shfl_xor(sm[r], 4);
        sm[r] += __shfl_xor(sm[r], 8);
        sm[r] = 1.f / sm[r];
    }

    __syncthreads();
#pragma unroll
    for (int tl = 0; tl < 13; ++tl)
#pragma unroll
        for (int r = 0; r < 4; ++r) {
            __half pv = __float2half(sc[tl][r] * sm[r]);
            Psh[((wave << 4) + (fq << 2) + r) * PT + (tl << 4) + fr] = *(short*)&pv;
        }
    __syncthreads();

    f32x4 o[4] = {};
    const int pra = (wave << 4) + fr;
#pragma unroll
    for (int s = 0; s < 6; ++s) {
        half8 pa = *(const half8*)&Psh[pra * PT + (fq << 3) + (s << 5)];
#pragma unroll
        for (int dt = 0; dt < 4; ++dt) {
            half8 vbf = *(const half8*)&Vt[((dt << 4) + fr) * PT + (fq << 3) + (s << 5)];
            o[dt] = __builtin_amdgcn_mfma_f32_16x16x32_f16(pa, vbf, o[dt], 0, 0, 0);
        }
    }
    {
        half4 pa = *(const half4*)&Psh[pra * PT + 192 + (fq << 2)];
#pragma unroll
        for (int dt = 0; dt < 4; ++dt) {
            half4 vbf = *(const half4*)&Vt[((dt << 4) + fr) * PT + 192 + (fq << 2)];
            o[dt] = __builtin_amdgcn_mfma_f32_16x16x16f16(pa, vbf, o[dt], 0, 0, 0);
        }
    }

#pragma unroll
    for (int r = 0; r < 4; ++r) {
        float ss = o[0][r]*o[0][r] + o[1][r]*o[1][r] + o[2][r]*o[2][r] + o[3][r]*o[3][r];
        ss += __shfl_xor(ss, 1); ss += __shfl_xor(ss, 2);
        ss += __shfl_xor(ss, 4); ss += __shfl_xor(ss, 8);
        const size_t rowb = (((size_t)(b << 12) + lq[r]) << 8) + h * 64;
#pragma unroll
        for (int dt = 0; dt < 4; ++dt)
            attn_o[rowb + (dt << 4) + fr] = o[dt][r];
        if (fr == 0) sumsq4[(((b << 12) + lq[r]) << 2) + h] = ss;
    }
}

extern "C" void kernel_launch(void* const* d_in, const int* in_sizes, int n_in,
                              void* d_out, int out_size, void* d_ws, size_t ws_size,
                              hipStream_t stream)
{
    const float* x      = (const float*)d_in[0];
    const float* W_qkv  = (const float*)d_in[1];
    const float* w_qn   = (const float*)d_in[2];
    const float* w_kn   = (const float*)d_in[3];
    const float* W_wp   = (const float*)d_in[4];
    const float* b_wp   = (const float*)d_in[5];
    const float* w_on   = (const float*)d_in[6];
    const float* W_out  = (const float*)d_in[7];
    const float* W_gate = (const float*)d_in[8];
    const float* b_gate = (const float*)d_in[9];
    float* out = (float*)d_out;

    float*  v32    = (float*)d_ws;                  // 8192*256 f32
    __half* qhp    = (__half*)(v32 + 8192 * 256);   // 8192*256 f16
    __half* khp    = qhp + 8192 * 256;
    __half* vhp    = khp + 8192 * 256;
    float*  attn_o = (float*)(vhp + 8192 * 256);    // 8192*256 f32
    float*  widthp = attn_o + 8192 * 256;
    float*  sharpp = widthp + 8192 * 4;
    float*  sumsq4 = sharpp + 8192 * 4;             // 8192*4
    float*  merged = (float*)qhp;                   // qh/kh dead after attn -> reuse 8MB

    // qkv GEMM + fused silu/rmsnorm/rope -> fp16 q,k,v (+ fp32 v)
    gemm_qkv<<<dim3(6, 64), 256, 0, stream>>>(x, W_qkv, w_qn, w_kn, qhp, khp, vhp, v32);
    // width / sharpness
    wp_kernel<<<256, 256, 0, stream>>>(x, W_wp, b_wp, widthp, sharpp);
    // patch-GEMM local attention (raw O + sumsq)
    attn_mfma<<<dim3(64, 4, 2), 256, 0, stream>>>(qhp, khp, vhp, widthp, sharpp,
                                                  attn_o, sumsq4);
    // gate gemm + fused o-rmsnorm + merge
    gemm_mfma<1><<<dim3(2, 64), 256, 0, stream>>>(v32, 256, W_gate, 256, merged, 256,
                                                  b_gate, v32, 256, attn_o, sumsq4, w_on);
    // final silu(merged @ W_out)
    gemm_mfma<0><<<dim3(2, 64), 256, 0, stream>>>(merged, 256, W_out, 256, out, 256,
                                                  nullptr, nullptr, 0, nullptr, nullptr, nullptr);
}

// Round 7
// 169.688 us; speedup vs baseline: 2.7853x; 1.0337x over previous
//
#include <hip/hip_runtime.h>
#include <hip/hip_fp16.h>
#include <math.h>

__device__ __forceinline__ float sigm(float x)  { return 1.0f / (1.0f + __expf(-x)); }
__device__ __forceinline__ float siluf(float x) { return x * sigm(x); }

typedef _Float16 half8  __attribute__((ext_vector_type(8)));
typedef _Float16 half4  __attribute__((ext_vector_type(4)));
typedef float    f32x4  __attribute__((ext_vector_type(4)));

// async global->LDS, 16 B/lane: LDS dest = wave-uniform base + lane*16 (packed!)
__device__ __forceinline__ void gld16(const void* g, void* l) {
    __builtin_amdgcn_global_load_lds(
        (const __attribute__((address_space(1))) unsigned*)g,
        (__attribute__((address_space(3))) unsigned*)l, 16, 0, 0);
}

// =======================================================================
// Split-fp32 GEMM core via f16 hi/lo MFMA (x = hi + lo, residual 2^-22):
// acc = A[128x256] @ B[256x128].  Staging is pure global_load_lds (no VGPR
// round-trip, no in-loop conversion).  LDS rows packed 64 B (GLD requires
// it); bank-start (row*16+fq*4)%32 -> 2-way = free.
// AMODE 0: A blocked [kb][8192][32] (contiguous 1 KB per GLD)
// AMODE 1: A row-major [m][256] halves (per-lane strided global, fine)
// B always blocked [kb][nbs][32].
// =======================================================================
template <int AMODE>
__device__ __forceinline__ void gemm_core16(
    const __half* __restrict__ Ahi, const __half* __restrict__ Alo,
    const __half* __restrict__ Bhi, const __half* __restrict__ Blo,
    int nbs, int m0, int n0, int t, f32x4 (&acc)[4][4])
{
    __shared__ short AsHi[4096], AsLo[4096], BsHi[4096], BsLo[4096];  // 8 KB each
    const int lane = t & 63, wave = t >> 6;
    const int wm = (wave >> 1) << 6, wn = (wave & 1) << 6;
    const int fr = lane & 15, fq = lane >> 4;
    const int r0 = wave << 5;   // this wave's 32 staging rows

    for (int kb = 0; kb < 8; ++kb) {
        __syncthreads();        // prev step's frag reads done before overwrite
#pragma unroll
        for (int hf = 0; hf < 2; ++hf) {
            const int rr = r0 + (hf << 4);      // 16-row chunk = 1 KB
            size_t ga;
            if (AMODE == 0)
                ga = (((size_t)(kb * 8192 + m0 + rr)) << 5) + (lane << 3);
            else
                ga = (((size_t)(m0 + rr + (lane >> 2))) << 8) + (kb << 5) + ((lane & 3) << 3);
            gld16(Ahi + ga, &AsHi[rr << 5]);
            gld16(Alo + ga, &AsLo[rr << 5]);
            const size_t gb = (((size_t)(kb * nbs + n0 + rr)) << 5) + (lane << 3);
            gld16(Bhi + gb, &BsHi[rr << 5]);
            gld16(Blo + gb, &BsLo[rr << 5]);
        }
        __syncthreads();        // barrier drains vmcnt -> LDS valid

        half8 ah[4], al[4], bh[4], bl[4];
#pragma unroll
        for (int i = 0; i < 4; ++i) {
            const int aoff = ((wm + (i << 4) + fr) << 5) + (fq << 3);
            ah[i] = *(const half8*)&AsHi[aoff];
            al[i] = *(const half8*)&AsLo[aoff];
            const int boff = ((wn + (i << 4) + fr) << 5) + (fq << 3);
            bh[i] = *(const half8*)&BsHi[boff];
            bl[i] = *(const half8*)&BsLo[boff];
        }
#pragma unroll
        for (int mi = 0; mi < 4; ++mi)
#pragma unroll
            for (int ni = 0; ni < 4; ++ni) {
                acc[mi][ni] = __builtin_amdgcn_mfma_f32_16x16x32_f16(ah[mi], bh[ni], acc[mi][ni], 0, 0, 0);
                acc[mi][ni] = __builtin_amdgcn_mfma_f32_16x16x32_f16(al[mi], bh[ni], acc[mi][ni], 0, 0, 0);
                acc[mi][ni] = __builtin_amdgcn_mfma_f32_16x16x32_f16(ah[mi], bl[ni], acc[mi][ni], 0, 0, 0);
            }
    }
}

// =======================================================================
// Prep: x -> f16 hi/lo (k-blocked) + wp(width/sharp);  W_qkv/W_gate/W_out
// -> transposed [kb][n][32] f16 hi/lo.  One kernel, branch per block.
// =======================================================================
__global__ __launch_bounds__(256) void prep_kernel(
    const float* __restrict__ x, const float* __restrict__ Wqkv,
    const float* __restrict__ Wgate, const float* __restrict__ Wout,
    const float* __restrict__ Wwp, const float* __restrict__ bwp,
    __half* __restrict__ xhi, __half* __restrict__ xlo,
    __half* __restrict__ wqh, __half* __restrict__ wql,
    __half* __restrict__ wgh, __half* __restrict__ wgl,
    __half* __restrict__ woh, __half* __restrict__ wol,
    float* __restrict__ width, float* __restrict__ sharp)
{
    __shared__ float xs[32][260];
    const int t = threadIdx.x;
    const int blk = blockIdx.x;
    if (blk < 256) {
        const int row0 = blk << 5;
        for (int e = t; e < 2048; e += 256) {
            int r = e >> 6, cc = (e & 63) << 2;
            *(float4*)&xs[r][cc] = *(const float4*)&x[(size_t)(row0 + r) * 256 + cc];
        }
        __syncthreads();
        const int r = t >> 3, kb = t & 7;
        __half hibuf[32], lobuf[32];
#pragma unroll
        for (int i = 0; i < 32; ++i) {
            float v = xs[r][(kb << 5) + i];
            __half hv = __float2half(v);
            hibuf[i] = hv;
            lobuf[i] = __float2half(v - __half2float(hv));
        }
        const size_t ob = ((size_t)(kb * 8192 + row0 + r)) << 5;
#pragma unroll
        for (int i = 0; i < 4; ++i) {
            *(int4*)&xhi[ob + (i << 3)] = *(int4*)&hibuf[i << 3];
            *(int4*)&xlo[ob + (i << 3)] = *(int4*)&lobuf[i << 3];
        }
        // wp: thread (r, n=kb)
        float acc = 0.f;
#pragma unroll 8
        for (int k = 0; k < 256; ++k) acc += xs[r][k] * Wwp[k * 8 + kb];
        float s = sigm(siluf(acc + bwp[kb]));
        const int row = row0 + r;
        if (kb < 4) width[row * 4 + kb] = s * 4.242640687119285f + 0.5f;  // sqrt(18)
        else        sharp[row * 4 + kb - 4] = s * 9.5f + 0.5f;
    } else {
        const float* W; __half *Whi, *Wlo; int N, nb0, ncnt;
        if (blk < 288)      { W = Wqkv;  Whi = wqh; Wlo = wql; N = 768; nb0 = (blk - 256) * 24; ncnt = 24; }
        else if (blk < 296) { W = Wgate; Whi = wgh; Wlo = wgl; N = 256; nb0 = (blk - 288) * 32; ncnt = 32; }
        else                { W = Wout;  Whi = woh; Wlo = wol; N = 256; nb0 = (blk - 296) * 32; ncnt = 32; }
        for (int j = 0; j < ncnt; ++j)
            xs[j][t] = W[(size_t)t * N + nb0 + j];   // t = k row
        __syncthreads();
        for (int c = t; c < ncnt * 8; c += 256) {
            const int j = c >> 3, kb = c & 7;
            __half hibuf[32], lobuf[32];
#pragma unroll
            for (int i = 0; i < 32; ++i) {
                float v = xs[j][(kb << 5) + i];
                __half hv = __float2half(v);
                hibuf[i] = hv;
                lobuf[i] = __float2half(v - __half2float(hv));
            }
            const size_t ob = ((size_t)(kb * N + nb0 + j)) << 5;
#pragma unroll
            for (int i = 0; i < 4; ++i) {
                *(int4*)&Whi[ob + (i << 3)] = *(int4*)&hibuf[i << 3];
                *(int4*)&Wlo[ob + (i << 3)] = *(int4*)&lobuf[i << 3];
            }
        }
    }
}

// =======================================================================
// qkv GEMM + fused silu -> rmsnorm(D=64) -> RoPE(pos=head) -> f16 stores.
// v written as f16 hi/lo pair (feeds gate GEMM staging + merge epilogue).
// =======================================================================
__global__ __launch_bounds__(256, 2) void gemm_qkv(
    const __half* __restrict__ xhi, const __half* __restrict__ xlo,
    const __half* __restrict__ wqh, const __half* __restrict__ wql,
    const float* __restrict__ wq, const float* __restrict__ wk,
    __half* __restrict__ qh, __half* __restrict__ kh,
    __half* __restrict__ vh, __half* __restrict__ vlo)
{
    const int t  = threadIdx.x;
    const int m0 = blockIdx.y << 7, n0 = blockIdx.x << 7;
    f32x4 acc[4][4] = {};
    gemm_core16<0>(xhi, xlo, wqh, wql, 768, m0, n0, t, acc);

    const int lane = t & 63, wave = t >> 6;
    const int wm = (wave >> 1) << 6, wn = (wave & 1) << 6;
    const int fr = lane & 15, fq = lane >> 4;
    const int gc0 = n0 + wn;
    const int seg = gc0 >> 8;          // 0=q, 1=k, 2=v
    const int h   = (gc0 >> 6) & 3;
    const int hc0 = h << 6;

#pragma unroll
    for (int mi = 0; mi < 4; ++mi)
#pragma unroll
        for (int ni = 0; ni < 4; ++ni)
#pragma unroll
            for (int r = 0; r < 4; ++r)
                acc[mi][ni][r] = siluf(acc[mi][ni][r]);

    if (seg == 2) {
#pragma unroll
        for (int mi = 0; mi < 4; ++mi)
#pragma unroll
            for (int r = 0; r < 4; ++r) {
                const size_t row = m0 + wm + (mi << 4) + (fq << 2) + r;
#pragma unroll
                for (int ni = 0; ni < 4; ++ni) {
                    const int c = hc0 + (ni << 4) + fr;
                    const float v = acc[mi][ni][r];
                    const __half hv = __float2half(v);
                    vh[row * 256 + c]  = hv;
                    vlo[row * 256 + c] = __float2half(v - __half2float(hv));
                }
            }
    } else {
        const float* wnorm = seg ? wk : wq;
        float wv[4];
#pragma unroll
        for (int ni = 0; ni < 4; ++ni) wv[ni] = wnorm[(ni << 4) + fr];
        float cs[2], sn[2];
#pragma unroll
        for (int j = 0; j < 2; ++j) {
            const int d = (j << 4) + fr;
            const float freq = powf(10000.f, -(float)d * (1.f / 32.f));
            const float ang = (float)h * freq;    // pos = arange(H) reference quirk
            cs[j] = cosf(ang); sn[j] = sinf(ang);
        }
        __half* dstbase = (seg ? kh : qh);
#pragma unroll
        for (int mi = 0; mi < 4; ++mi)
#pragma unroll
            for (int r = 0; r < 4; ++r) {
                float ss = acc[mi][0][r] * acc[mi][0][r] + acc[mi][1][r] * acc[mi][1][r]
                         + acc[mi][2][r] * acc[mi][2][r] + acc[mi][3][r] * acc[mi][3][r];
                ss += __shfl_xor(ss, 1); ss += __shfl_xor(ss, 2);
                ss += __shfl_xor(ss, 4); ss += __shfl_xor(ss, 8);
                const float rinv = 1.f / sqrtf(ss * (1.f / 64.f) + 1e-6f);
                float xv[4];
#pragma unroll
                for (int ni = 0; ni < 4; ++ni) xv[ni] = acc[mi][ni][r] * rinv * wv[ni];
                const float o0 = xv[0] * cs[0] - xv[2] * sn[0];
                const float o2 = xv[0] * sn[0] + xv[2] * cs[0];
                const float o1 = xv[1] * cs[1] - xv[3] * sn[1];
                const float o3 = xv[1] * sn[1] + xv[3] * cs[1];
                const size_t row = m0 + wm + (mi << 4) + (fq << 2) + r;
                __half* dst = dstbase + row * 256 + hc0;
                dst[fr]      = __float2half(o0);
                dst[16 + fr] = __float2half(o1);
                dst[32 + fr] = __float2half(o2);
                dst[48 + fr] = __float2half(o3);
            }
    }
}

// ---- gate GEMM + fused o-rmsnorm + merge -> merged f16 hi/lo ----
__global__ __launch_bounds__(256, 2) void gemm_gate(
    const __half* __restrict__ vh, const __half* __restrict__ vlo,
    const __half* __restrict__ wgh, const __half* __restrict__ wgl,
    const float* __restrict__ bias, const float* __restrict__ attn_o,
    const float* __restrict__ sumsq4, const float* __restrict__ w_onorm,
    __half* __restrict__ mh, __half* __restrict__ mlo)
{
    const int t  = threadIdx.x;
    const int m0 = blockIdx.y << 7, n0 = blockIdx.x << 7;
    f32x4 acc[4][4] = {};
    gemm_core16<1>(vh, vlo, wgh, wgl, 256, m0, n0, t, acc);

    const int lane = t & 63, wave = t >> 6;
    const int wm = (wave >> 1) << 6, wn = (wave & 1) << 6;
    const int fr = lane & 15, fq = lane >> 4;

    float rmsf[4][4];
#pragma unroll
    for (int mi = 0; mi < 4; ++mi)
#pragma unroll
        for (int r = 0; r < 4; ++r) {
            const int m = m0 + wm + (mi << 4) + (fq << 2) + r;
            float4 s4 = *(const float4*)&sumsq4[(size_t)m * 4];
            rmsf[mi][r] = 1.f / sqrtf((s4.x + s4.y + s4.z + s4.w) * (1.f / 256.f) + 1e-6f);
        }

#pragma unroll
    for (int mi = 0; mi < 4; ++mi)
#pragma unroll
        for (int ni = 0; ni < 4; ++ni) {
            const int n  = n0 + wn + (ni << 4) + fr;
            const int mb = m0 + wm + (mi << 4) + (fq << 2);
            const float bb  = bias[n];
            const float won = w_onorm[n];
#pragma unroll
            for (int r = 0; r < 4; ++r) {
                const int m = mb + r;
                const float g  = sigm(siluf(acc[mi][ni][r] + bb));
                const float vv = __half2float(vh[(size_t)m * 256 + n])
                               + __half2float(vlo[(size_t)m * 256 + n]);
                const float oo = attn_o[(size_t)m * 256 + n] * rmsf[mi][r] * won;
                const float mg = g * vv + (1.f - g) * oo;
                const __half hv = __float2half(mg);
                mh[(size_t)m * 256 + n]  = hv;
                mlo[(size_t)m * 256 + n] = __float2half(mg - __half2float(hv));
            }
        }
}

// ---- final: out = silu(merged @ W_out) ----
__global__ __launch_bounds__(256, 2) void gemm_out(
    const __half* __restrict__ mh, const __half* __restrict__ mlo,
    const __half* __restrict__ woh, const __half* __restrict__ wol,
    float* __restrict__ out)
{
    const int t  = threadIdx.x;
    const int m0 = blockIdx.y << 7, n0 = blockIdx.x << 7;
    f32x4 acc[4][4] = {};
    gemm_core16<1>(mh, mlo, woh, wol, 256, m0, n0, t, acc);

    const int lane = t & 63, wave = t >> 6;
    const int wm = (wave >> 1) << 6, wn = (wave & 1) << 6;
    const int fr = lane & 15, fq = lane >> 4;
#pragma unroll
    for (int mi = 0; mi < 4; ++mi)
#pragma unroll
        for (int ni = 0; ni < 4; ++ni) {
            const int n  = n0 + wn + (ni << 4) + fr;
            const int mb = m0 + wm + (mi << 4) + (fq << 2);
#pragma unroll
            for (int r = 0; r < 4; ++r)
                out[(size_t)(mb + r) * 256 + n] = siluf(acc[mi][ni][r]);
        }
}

// =======================================================================
// Patch-GEMM local attention (unchanged from R5/R6).
// =======================================================================
#define PT 216   // P / Vt row stride (halves)

__global__ __launch_bounds__(256, 2) void attn_mfma(
    const __half* __restrict__ qh, const __half* __restrict__ kh,
    const __half* __restrict__ vh, const float* __restrict__ width,
    const float* __restrict__ sharp, float* __restrict__ attn_o,
    float* __restrict__ sumsq4)
{
    __shared__ short smem[31744];          // 63488 B
    short* Ksh = smem;                     // [208][64] chunk-swizzled; overlaid by P
    short* Psh = smem;
    short* Vt  = smem + 13824;             // [64 d][PT]
    short* Qsh = smem + 27648;             // [64 q][64] chunk-swizzled

    const int t = threadIdx.x;
    const int lane = t & 63, wave = t >> 6;
    const int fr = lane & 15, fq = lane >> 4;
    const int patch = blockIdx.x, h = blockIdx.y, b = blockIdx.z;
    const int pr0 = (patch >> 3) << 3, pc0 = (patch & 7) << 3;

    float wd[4], sh[4]; int lq[4];
#pragma unroll
    for (int r = 0; r < 4; ++r) {
        const int q = (wave << 4) + (fq << 2) + r;
        lq[r] = (pr0 + (q >> 3)) * 64 + pc0 + (q & 7);
        wd[r] = width[((b << 12) + lq[r]) * 4 + h];
        sh[r] = sharp[((b << 12) + lq[r]) * 4 + h];
    }

    const int srow = t >> 5;
    const int d2 = (t & 31) << 1;
    const size_t cbase = (((size_t)b << 12) * 256) + (size_t)h * 64 + d2;

    unsigned kb[25], vb[25];
#pragma unroll
    for (int p5 = 0; p5 < 25; ++p5) {
        const int prow = p5 * 8 + srow;
        const int pi = prow / 14, pj = prow - pi * 14;
        const int gr = pr0 - 3 + pi, gc = pc0 - 3 + pj;
        const bool ok = (prow < 196) & ((unsigned)gr < 64u) & ((unsigned)gc < 64u);
        const int grc = min(max(gr, 0), 63), gcc = min(max(gc, 0), 63);
        const size_t off = cbase + (size_t)(grc * 64 + gcc) * 256;
        unsigned kv = *(const unsigned*)(kh + off);
        unsigned vv = *(const unsigned*)(vh + off);
        kb[p5] = ok ? kv : 0u;
        vb[p5] = ok ? vv : 0u;
    }
    unsigned qb[8];
#pragma unroll
    for (int p5 = 0; p5 < 8; ++p5) {
        const int q = p5 * 8 + srow;
        const int l = (pr0 + (q >> 3)) * 64 + pc0 + (q & 7);
        qb[p5] = *(const unsigned*)(qh + cbase + (size_t)l * 256);
    }

    const int chunk = d2 >> 3, dlo = d2 & 7;
#pragma unroll
    for (int p5 = 0; p5 < 25; ++p5) {
        const int prow = p5 * 8 + srow;
        *(unsigned*)&Ksh[(prow << 6) + ((chunk ^ (prow & 7)) << 3) + dlo] = kb[p5];
        Vt[(d2)     * PT + prow] = (short)(vb[p5] & 0xffffu);
        Vt[(d2 + 1) * PT + prow] = (short)(vb[p5] >> 16);
    }
#pragma unroll
    for (int p5 = 0; p5 < 8; ++p5) {
        const int q = p5 * 8 + srow;
        *(unsigned*)&Qsh[(q << 6) + ((chunk ^ (q & 7)) << 3) + dlo] = qb[p5];
    }
    for (int i = t; i < 64 * 20; i += 256)
        Vt[(i / 20) * PT + 196 + (i % 20)] = 0;
    __syncthreads();

    const int qrow = (wave << 4) + fr;
    half8 a0 = *(const half8*)&Qsh[(qrow << 6) + (((0 + fq) ^ (qrow & 7)) << 3)];
    half8 a1 = *(const half8*)&Qsh[(qrow << 6) + (((4 + fq) ^ (qrow & 7)) << 3)];
    f32x4 sc[13];
#pragma unroll
    for (int tl = 0; tl < 13; ++tl) {
        const int kr = (tl << 4) + fr;
        half8 b0 = *(const half8*)&Ksh[(kr << 6) + (((0 + fq) ^ (kr & 7)) << 3)];
        half8 b1 = *(const half8*)&Ksh[(kr << 6) + (((4 + fq) ^ (kr & 7)) << 3)];
        f32x4 z = {0.f, 0.f, 0.f, 0.f};
        z = __builtin_amdgcn_mfma_f32_16x16x32_f16(a0, b0, z, 0, 0, 0);
        sc[tl] = __builtin_amdgcn_mfma_f32_16x16x32_f16(a1, b1, z, 0, 0, 0);
    }

    float mx[4] = {-3e38f, -3e38f, -3e38f, -3e38f};
#pragma unroll
    for (int tl = 0; tl < 13; ++tl) {
        const int p = (tl << 4) + fr;
        const int pi = p / 14, pj = p - pi * 14;
        const bool pvld = p < 196;
#pragma unroll
        for (int r = 0; r < 4; ++r) {
            const int q = (wave << 4) + (fq << 2) + r;
            const int di = pi - 3 - ((q >> 3) & 7), dj = pj - 3 - (q & 7);
            const bool win = pvld & ((unsigned)(di + 3) <= 6u) & ((unsigned)(dj + 3) <= 6u);
            const float rel = sqrtf((float)(di * di + dj * dj));
            const float mk = sigm((wd[r] - rel) * sh[r]);
            float s = sc[tl][r] * 0.125f - (1.f - mk) * 10000.f;
            s = win ? s : -3e38f;
            sc[tl][r] = s;
            mx[r] = fmaxf(mx[r], s);
        }
    }
#pragma unroll
    for (int r = 0; r < 4; ++r) {
        mx[r] = fmaxf(mx[r], __shfl_xor(mx[r], 1));
        mx[r] = fmaxf(mx[r], __shfl_xor(mx[r], 2));
        mx[r] = fmaxf(mx[r], __shfl_xor(mx[r], 4));
        mx[r] = fmaxf(mx[r], __shfl_xor(mx[r], 8));
    }
    float sm[4] = {0.f, 0.f, 0.f, 0.f};
#pragma unroll
    for (int tl = 0; tl < 13; ++tl)
#pragma unroll
        for (int r = 0; r < 4; ++r) {
            const float e = __expf(sc[tl][r] - mx[r]);
            sc[tl][r] = e; sm[r] += e;
        }
#pragma unroll
    for (int r = 0; r < 4; ++r) {
        sm[r] += __shfl_xor(sm[r], 1);
        sm[r] += __shfl_xor(sm[r], 2);
        sm[r] += __shfl_xor(sm[r], 4);
        sm[r] += __shfl_xor(sm[r], 8);
        sm[r] = 1.f / sm[r];
    }

    __syncthreads();
#pragma unroll
    for (int tl = 0; tl < 13; ++tl)
#pragma unroll
        for (int r = 0; r < 4; ++r) {
            __half pv = __float2half(sc[tl][r] * sm[r]);
            Psh[((wave << 4) + (fq << 2) + r) * PT + (tl << 4) + fr] = *(short*)&pv;
        }
    __syncthreads();

    f32x4 o[4] = {};
    const int pra = (wave << 4) + fr;
#pragma unroll
    for (int s = 0; s < 6; ++s) {
        half8 pa = *(const half8*)&Psh[pra * PT + (fq << 3) + (s << 5)];
#pragma unroll
        for (int dt = 0; dt < 4; ++dt) {
            half8 vbf = *(const half8*)&Vt[((dt << 4) + fr) * PT + (fq << 3) + (s << 5)];
            o[dt] = __builtin_amdgcn_mfma_f32_16x16x32_f16(pa, vbf, o[dt], 0, 0, 0);
        }
    }
    {
        half4 pa = *(const half4*)&Psh[pra * PT + 192 + (fq << 2)];
#pragma unroll
        for (int dt = 0; dt < 4; ++dt) {
            half4 vbf = *(const half4*)&Vt[((dt << 4) + fr) * PT + 192 + (fq << 2)];
            o[dt] = __builtin_amdgcn_mfma_f32_16x16x16f16(pa, vbf, o[dt], 0, 0, 0);
        }
    }

#pragma unroll
    for (int r = 0; r < 4; ++r) {
        float ss = o[0][r]*o[0][r] + o[1][r]*o[1][r] + o[2][r]*o[2][r] + o[3][r]*o[3][r];
        ss += __shfl_xor(ss, 1); ss += __shfl_xor(ss, 2);
        ss += __shfl_xor(ss, 4); ss += __shfl_xor(ss, 8);
        const size_t rowb = (((size_t)(b << 12) + lq[r]) << 8) + h * 64;
#pragma unroll
        for (int dt = 0; dt < 4; ++dt)
            attn_o[rowb + (dt << 4) + fr] = o[dt][r];
        if (fr == 0) sumsq4[(((b << 12) + lq[r]) << 2) + h] = ss;
    }
}

extern "C" void kernel_launch(void* const* d_in, const int* in_sizes, int n_in,
                              void* d_out, int out_size, void* d_ws, size_t ws_size,
                              hipStream_t stream)
{
    const float* x      = (const float*)d_in[0];
    const float* W_qkv  = (const float*)d_in[1];
    const float* w_qn   = (const float*)d_in[2];
    const float* w_kn   = (const float*)d_in[3];
    const float* W_wp   = (const float*)d_in[4];
    const float* b_wp   = (const float*)d_in[5];
    const float* w_on   = (const float*)d_in[6];
    const float* W_out  = (const float*)d_in[7];
    const float* W_gate = (const float*)d_in[8];
    const float* b_gate = (const float*)d_in[9];
    float* out = (float*)d_out;

    __half* ws16 = (__half*)d_ws;
    __half* xhi = ws16;                    // [8][8192][32]
    __half* xlo = xhi + 2097152;
    __half* wqh = xlo + 2097152;           // [8][768][32]
    __half* wql = wqh + 196608;
    __half* wgh = wql + 196608;            // [8][256][32]
    __half* wgl = wgh + 65536;
    __half* woh = wgl + 65536;
    __half* wol = woh + 65536;
    __half* qhp = wol + 65536;             // [8192][256]
    __half* khp = qhp + 2097152;
    __half* vhp = khp + 2097152;
    __half* vlo = vhp + 2097152;
    __half* mh  = vlo + 2097152;
    __half* mlo = mh + 2097152;
    float* attn_o = (float*)(mlo + 2097152);  // [8192][256] f32
    float* widthp = attn_o + 2097152;
    float* sharpp = widthp + 32768;
    float* sumsq4 = sharpp + 32768;

    // x -> f16 hi/lo blocked + wp; weights -> transposed f16 hi/lo blocked
    prep_kernel<<<304, 256, 0, stream>>>(x, W_qkv, W_gate, W_out, W_wp, b_wp,
                                         xhi, xlo, wqh, wql, wgh, wgl, woh, wol,
                                         widthp, sharpp);
    // qkv GEMM (GLD staging) + fused silu/rmsnorm/rope -> q,k,v f16 (+ v-lo)
    gemm_qkv<<<dim3(6, 64), 256, 0, stream>>>(xhi, xlo, wqh, wql, w_qn, w_kn,
                                              qhp, khp, vhp, vlo);
    // patch-GEMM local attention (raw O + sumsq)
    attn_mfma<<<dim3(64, 4, 2), 256, 0, stream>>>(qhp, khp, vhp, widthp, sharpp,
                                                  attn_o, sumsq4);
    // gate gemm + fused o-rmsnorm + merge -> merged f16 hi/lo
    gemm_gate<<<dim3(2, 64), 256, 0, stream>>>(vhp, vlo, wgh, wgl, b_gate,
                                               attn_o, sumsq4, w_on, mh, mlo);
    // final silu(merged @ W_out)
    gemm_out<<<dim3(2, 64), 256, 0, stream>>>(mh, mlo, woh, wol, out);
}

// Round 8
// 155.792 us; speedup vs baseline: 3.0337x; 1.0892x over previous
//
#include <hip/hip_runtime.h>
#include <hip/hip_fp16.h>
#include <math.h>

__device__ __forceinline__ float sigm(float x)  { return 1.0f / (1.0f + __expf(-x)); }
__device__ __forceinline__ float siluf(float x) { return x * sigm(x); }

typedef _Float16 half8  __attribute__((ext_vector_type(8)));
typedef _Float16 half4  __attribute__((ext_vector_type(4)));
typedef float    f32x4  __attribute__((ext_vector_type(4)));

// async global->LDS, 16 B/lane: LDS dest = wave-uniform base + lane*16 (packed!)
__device__ __forceinline__ void gld16(const void* g, void* l) {
    __builtin_amdgcn_global_load_lds(
        (const __attribute__((address_space(1))) unsigned*)g,
        (__attribute__((address_space(3))) unsigned*)l, 16, 0, 0);
}

// =======================================================================
// 2-term split GEMM core: acc = A_f16[.x256] @ (Bhi + Blo)[256x128].
// A quantized to single f16 (error ~2^-12 rel, below downstream f16 store
// rounding); B exact as f16 hi+lo pair -> 2 MFMA per frag pair.
// MI = m-frags per wave (wave m-extent MI*16; block m = MI*32).
// AMODE 0: A k-blocked [kb][8192][32]; AMODE 1: A row-major [m][256].
// =======================================================================
template <int MI, int AMODE>
__device__ __forceinline__ void gemm_core16(
    const __half* __restrict__ A16,
    const __half* __restrict__ Bhi, const __half* __restrict__ Blo,
    int nbs, int m0, int n0, int t, f32x4 (&acc)[MI][4])
{
    __shared__ short As[MI * 1024], BsHi[4096], BsLo[4096];
    const int lane = t & 63, wave = t >> 6;
    const int wm = (wave >> 1) * (MI << 4), wn = (wave & 1) << 6;
    const int fr = lane & 15, fq = lane >> 4;

    for (int kb = 0; kb < 8; ++kb) {
        __syncthreads();        // prev step's frag reads done before overwrite
#pragma unroll
        for (int hf = 0; hf < MI / 2; ++hf) {          // A: MI*8 rows/wave
            const int rr = wave * (MI << 3) + (hf << 4);
            size_t ga;
            if (AMODE == 0)
                ga = (((size_t)(kb * 8192 + m0 + rr)) << 5) + (lane << 3);
            else
                ga = (((size_t)(m0 + rr + (lane >> 2))) << 8) + (kb << 5) + ((lane & 3) << 3);
            gld16(A16 + ga, &As[rr << 5]);
        }
#pragma unroll
        for (int hf = 0; hf < 2; ++hf) {               // B: 32 rows/wave
            const int rr = (wave << 5) + (hf << 4);
            const size_t gb = (((size_t)(kb * nbs + n0 + rr)) << 5) + (lane << 3);
            gld16(Bhi + gb, &BsHi[rr << 5]);
            gld16(Blo + gb, &BsLo[rr << 5]);
        }
        __syncthreads();        // barrier drains vmcnt -> LDS valid

        half8 a[MI], bh[4], bl[4];
#pragma unroll
        for (int i = 0; i < MI; ++i)
            a[i] = *(const half8*)&As[((wm + (i << 4) + fr) << 5) + (fq << 3)];
#pragma unroll
        for (int i = 0; i < 4; ++i) {
            const int boff = ((wn + (i << 4) + fr) << 5) + (fq << 3);
            bh[i] = *(const half8*)&BsHi[boff];
            bl[i] = *(const half8*)&BsLo[boff];
        }
#pragma unroll
        for (int mi = 0; mi < MI; ++mi)
#pragma unroll
            for (int ni = 0; ni < 4; ++ni) {
                acc[mi][ni] = __builtin_amdgcn_mfma_f32_16x16x32_f16(a[mi], bh[ni], acc[mi][ni], 0, 0, 0);
                acc[mi][ni] = __builtin_amdgcn_mfma_f32_16x16x32_f16(a[mi], bl[ni], acc[mi][ni], 0, 0, 0);
            }
    }
}

// =======================================================================
// Prep: x -> f16 single (k-blocked) + wp(width/sharp); weights -> [kb][n][32]
// f16 hi/lo. One kernel, branch per block.
// =======================================================================
__global__ __launch_bounds__(256) void prep_kernel(
    const float* __restrict__ x, const float* __restrict__ Wqkv,
    const float* __restrict__ Wgate, const float* __restrict__ Wout,
    const float* __restrict__ Wwp, const float* __restrict__ bwp,
    __half* __restrict__ xh,
    __half* __restrict__ wqh, __half* __restrict__ wql,
    __half* __restrict__ wgh, __half* __restrict__ wgl,
    __half* __restrict__ woh, __half* __restrict__ wol,
    float* __restrict__ width, float* __restrict__ sharp)
{
    __shared__ float xs[32][260];
    const int t = threadIdx.x;
    const int blk = blockIdx.x;
    if (blk < 256) {
        const int row0 = blk << 5;
        for (int e = t; e < 2048; e += 256) {
            int r = e >> 6, cc = (e & 63) << 2;
            *(float4*)&xs[r][cc] = *(const float4*)&x[(size_t)(row0 + r) * 256 + cc];
        }
        __syncthreads();
        const int r = t >> 3, kb = t & 7;
        __half hibuf[32];
#pragma unroll
        for (int i = 0; i < 32; ++i)
            hibuf[i] = __float2half(xs[r][(kb << 5) + i]);
        const size_t ob = ((size_t)(kb * 8192 + row0 + r)) << 5;
#pragma unroll
        for (int i = 0; i < 4; ++i)
            *(int4*)&xh[ob + (i << 3)] = *(int4*)&hibuf[i << 3];
        // wp: thread (r, n=kb)
        float acc = 0.f;
#pragma unroll 8
        for (int k = 0; k < 256; ++k) acc += xs[r][k] * Wwp[k * 8 + kb];
        float s = sigm(siluf(acc + bwp[kb]));
        const int row = row0 + r;
        if (kb < 4) width[row * 4 + kb] = s * 4.242640687119285f + 0.5f;  // sqrt(18)
        else        sharp[row * 4 + kb - 4] = s * 9.5f + 0.5f;
    } else {
        const float* W; __half *Whi, *Wlo; int N, nb0, ncnt;
        if (blk < 288)      { W = Wqkv;  Whi = wqh; Wlo = wql; N = 768; nb0 = (blk - 256) * 24; ncnt = 24; }
        else if (blk < 296) { W = Wgate; Whi = wgh; Wlo = wgl; N = 256; nb0 = (blk - 288) * 32; ncnt = 32; }
        else                { W = Wout;  Whi = woh; Wlo = wol; N = 256; nb0 = (blk - 296) * 32; ncnt = 32; }
        for (int j = 0; j < ncnt; ++j)
            xs[j][t] = W[(size_t)t * N + nb0 + j];   // t = k row
        __syncthreads();
        for (int c = t; c < ncnt * 8; c += 256) {
            const int j = c >> 3, kb = c & 7;
            __half hibuf[32], lobuf[32];
#pragma unroll
            for (int i = 0; i < 32; ++i) {
                float v = xs[j][(kb << 5) + i];
                __half hv = __float2half(v);
                hibuf[i] = hv;
                lobuf[i] = __float2half(v - __half2float(hv));
            }
            const size_t ob = ((size_t)(kb * N + nb0 + j)) << 5;
#pragma unroll
            for (int i = 0; i < 4; ++i) {
                *(int4*)&Whi[ob + (i << 3)] = *(int4*)&hibuf[i << 3];
                *(int4*)&Wlo[ob + (i << 3)] = *(int4*)&lobuf[i << 3];
            }
        }
    }
}

// =======================================================================
// qkv GEMM + fused silu -> rmsnorm(D=64) -> RoPE(pos=head) -> f16 stores.
// =======================================================================
__global__ __launch_bounds__(256, 3) void gemm_qkv(
    const __half* __restrict__ xh,
    const __half* __restrict__ wqh, const __half* __restrict__ wql,
    const float* __restrict__ wq, const float* __restrict__ wk,
    __half* __restrict__ qh, __half* __restrict__ kh, __half* __restrict__ vh)
{
    const int t  = threadIdx.x;
    const int m0 = blockIdx.y << 7, n0 = blockIdx.x << 7;
    f32x4 acc[4][4] = {};
    gemm_core16<4, 0>(xh, wqh, wql, 768, m0, n0, t, acc);

    const int lane = t & 63, wave = t >> 6;
    const int wm = (wave >> 1) << 6, wn = (wave & 1) << 6;
    const int fr = lane & 15, fq = lane >> 4;
    const int gc0 = n0 + wn;
    const int seg = gc0 >> 8;          // 0=q, 1=k, 2=v
    const int h   = (gc0 >> 6) & 3;
    const int hc0 = h << 6;

#pragma unroll
    for (int mi = 0; mi < 4; ++mi)
#pragma unroll
        for (int ni = 0; ni < 4; ++ni)
#pragma unroll
            for (int r = 0; r < 4; ++r)
                acc[mi][ni][r] = siluf(acc[mi][ni][r]);

    if (seg == 2) {
#pragma unroll
        for (int mi = 0; mi < 4; ++mi)
#pragma unroll
            for (int r = 0; r < 4; ++r) {
                const size_t row = m0 + wm + (mi << 4) + (fq << 2) + r;
#pragma unroll
                for (int ni = 0; ni < 4; ++ni)
                    vh[row * 256 + hc0 + (ni << 4) + fr] = __float2half(acc[mi][ni][r]);
            }
    } else {
        const float* wnorm = seg ? wk : wq;
        float wv[4];
#pragma unroll
        for (int ni = 0; ni < 4; ++ni) wv[ni] = wnorm[(ni << 4) + fr];
        float cs[2], sn[2];
#pragma unroll
        for (int j = 0; j < 2; ++j) {
            const int d = (j << 4) + fr;
            const float freq = powf(10000.f, -(float)d * (1.f / 32.f));
            const float ang = (float)h * freq;    // pos = arange(H) reference quirk
            cs[j] = cosf(ang); sn[j] = sinf(ang);
        }
        __half* dstbase = (seg ? kh : qh);
#pragma unroll
        for (int mi = 0; mi < 4; ++mi)
#pragma unroll
            for (int r = 0; r < 4; ++r) {
                float ss = acc[mi][0][r] * acc[mi][0][r] + acc[mi][1][r] * acc[mi][1][r]
                         + acc[mi][2][r] * acc[mi][2][r] + acc[mi][3][r] * acc[mi][3][r];
                ss += __shfl_xor(ss, 1); ss += __shfl_xor(ss, 2);
                ss += __shfl_xor(ss, 4); ss += __shfl_xor(ss, 8);
                const float rinv = 1.f / sqrtf(ss * (1.f / 64.f) + 1e-6f);
                float xv[4];
#pragma unroll
                for (int ni = 0; ni < 4; ++ni) xv[ni] = acc[mi][ni][r] * rinv * wv[ni];
                const float o0 = xv[0] * cs[0] - xv[2] * sn[0];
                const float o2 = xv[0] * sn[0] + xv[2] * cs[0];
                const float o1 = xv[1] * cs[1] - xv[3] * sn[1];
                const float o3 = xv[1] * sn[1] + xv[3] * cs[1];
                const size_t row = m0 + wm + (mi << 4) + (fq << 2) + r;
                __half* dst = dstbase + row * 256 + hc0;
                dst[fr]      = __float2half(o0);
                dst[16 + fr] = __float2half(o1);
                dst[32 + fr] = __float2half(o2);
                dst[48 + fr] = __float2half(o3);
            }
    }
}

// ---- gate GEMM (64x128 tiles) + fused o-rmsnorm + merge -> merged f16 ----
__global__ __launch_bounds__(256, 3) void gemm_gate(
    const __half* __restrict__ vh,
    const __half* __restrict__ wgh, const __half* __restrict__ wgl,
    const float* __restrict__ bias, const float* __restrict__ attn_o,
    const float* __restrict__ sumsq4, const float* __restrict__ w_onorm,
    __half* __restrict__ mh)
{
    const int t  = threadIdx.x;
    const int m0 = blockIdx.y << 6, n0 = blockIdx.x << 7;
    f32x4 acc[2][4] = {};
    gemm_core16<2, 1>(vh, wgh, wgl, 256, m0, n0, t, acc);

    const int lane = t & 63, wave = t >> 6;
    const int wm = (wave >> 1) << 5, wn = (wave & 1) << 6;
    const int fr = lane & 15, fq = lane >> 4;

    float rmsf[2][4];
#pragma unroll
    for (int mi = 0; mi < 2; ++mi)
#pragma unroll
        for (int r = 0; r < 4; ++r) {
            const int m = m0 + wm + (mi << 4) + (fq << 2) + r;
            float4 s4 = *(const float4*)&sumsq4[(size_t)m * 4];
            rmsf[mi][r] = 1.f / sqrtf((s4.x + s4.y + s4.z + s4.w) * (1.f / 256.f) + 1e-6f);
        }

#pragma unroll
    for (int mi = 0; mi < 2; ++mi)
#pragma unroll
        for (int ni = 0; ni < 4; ++ni) {
            const int n  = n0 + wn + (ni << 4) + fr;
            const int mb = m0 + wm + (mi << 4) + (fq << 2);
            const float bb  = bias[n];
            const float won = w_onorm[n];
#pragma unroll
            for (int r = 0; r < 4; ++r) {
                const int m = mb + r;
                const float g  = sigm(siluf(acc[mi][ni][r] + bb));
                const float vv = __half2float(vh[(size_t)m * 256 + n]);
                const float oo = attn_o[(size_t)m * 256 + n] * rmsf[mi][r] * won;
                mh[(size_t)m * 256 + n] = __float2half(g * vv + (1.f - g) * oo);
            }
        }
}

// ---- final: out = silu(merged @ W_out), 64x128 tiles ----
__global__ __launch_bounds__(256, 3) void gemm_out(
    const __half* __restrict__ mh,
    const __half* __restrict__ woh, const __half* __restrict__ wol,
    float* __restrict__ out)
{
    const int t  = threadIdx.x;
    const int m0 = blockIdx.y << 6, n0 = blockIdx.x << 7;
    f32x4 acc[2][4] = {};
    gemm_core16<2, 1>(mh, woh, wol, 256, m0, n0, t, acc);

    const int lane = t & 63, wave = t >> 6;
    const int wm = (wave >> 1) << 5, wn = (wave & 1) << 6;
    const int fr = lane & 15, fq = lane >> 4;
#pragma unroll
    for (int mi = 0; mi < 2; ++mi)
#pragma unroll
        for (int ni = 0; ni < 4; ++ni) {
            const int n  = n0 + wn + (ni << 4) + fr;
            const int mb = m0 + wm + (mi << 4) + (fq << 2);
#pragma unroll
            for (int r = 0; r < 4; ++r)
                out[(size_t)(mb + r) * 256 + n] = siluf(acc[mi][ni][r]);
        }
}

// =======================================================================
// Patch-GEMM local attention.  R8: Q loaded straight into A-frags from
// global (A-layout is k-contiguous per lane) -> Qsh + 8 staged loads gone;
// LDS 55.3 KB.
// =======================================================================
#define PT 216   // P / Vt row stride (halves)

__global__ __launch_bounds__(256, 2) void attn_mfma(
    const __half* __restrict__ qh, const __half* __restrict__ kh,
    const __half* __restrict__ vh, const float* __restrict__ width,
    const float* __restrict__ sharp, float* __restrict__ attn_o,
    float* __restrict__ sumsq4)
{
    __shared__ short smem[27648];          // 55296 B
    short* Ksh = smem;                     // [208][64] chunk-swizzled; overlaid by P [64][PT]
    short* Psh = smem;
    short* Vt  = smem + 13824;             // [64 d][PT]

    const int t = threadIdx.x;
    const int lane = t & 63, wave = t >> 6;
    const int fr = lane & 15, fq = lane >> 4;
    const int patch = blockIdx.x, h = blockIdx.y, b = blockIdx.z;
    const int pr0 = (patch >> 3) << 3, pc0 = (patch & 7) << 3;

    float wd[4], sh[4]; int lq[4];
#pragma unroll
    for (int r = 0; r < 4; ++r) {
        const int q = (wave << 4) + (fq << 2) + r;
        lq[r] = (pr0 + (q >> 3)) * 64 + pc0 + (q & 7);
        wd[r] = width[((b << 12) + lq[r]) * 4 + h];
        sh[r] = sharp[((b << 12) + lq[r]) * 4 + h];
    }

    // ---- Q straight into A-frags: lane (fr,fq) needs row q=wave*16+fr,
    //      k = fq*8..fq*8+7 and +32 (contiguous half8 in global) ----
    const int qrow = (wave << 4) + fr;
    const int lqr = (pr0 + (qrow >> 3)) * 64 + pc0 + (qrow & 7);
    const __half* qptr = qh + (((size_t)(b << 12) + lqr) << 8) + (h << 6) + (fq << 3);
    half8 a0 = *(const half8*)qptr;
    half8 a1 = *(const half8*)(qptr + 32);

    // ---- K/V staging (clamped+select, single drain) ----
    const int srow = t >> 5;
    const int d2 = (t & 31) << 1;
    const size_t cbase = (((size_t)b << 12) * 256) + (size_t)h * 64 + d2;

    unsigned kb[25], vb[25];
#pragma unroll
    for (int p5 = 0; p5 < 25; ++p5) {
        const int prow = p5 * 8 + srow;
        const int pi = prow / 14, pj = prow - pi * 14;
        const int gr = pr0 - 3 + pi, gc = pc0 - 3 + pj;
        const bool ok = (prow < 196) & ((unsigned)gr < 64u) & ((unsigned)gc < 64u);
        const int grc = min(max(gr, 0), 63), gcc = min(max(gc, 0), 63);
        const size_t off = cbase + (size_t)(grc * 64 + gcc) * 256;
        unsigned kv = *(const unsigned*)(kh + off);
        unsigned vv = *(const unsigned*)(vh + off);
        kb[p5] = ok ? kv : 0u;
        vb[p5] = ok ? vv : 0u;
    }

    const int chunk = d2 >> 3, dlo = d2 & 7;
#pragma unroll
    for (int p5 = 0; p5 < 25; ++p5) {
        const int prow = p5 * 8 + srow;
        *(unsigned*)&Ksh[(prow << 6) + ((chunk ^ (prow & 7)) << 3) + dlo] = kb[p5];
        Vt[(d2)     * PT + prow] = (short)(vb[p5] & 0xffffu);
        Vt[(d2 + 1) * PT + prow] = (short)(vb[p5] >> 16);
    }
    // zero Ksh rows 200..207 (read by QK tile 12; never staged)
    if (t < 128) {
        const int rr = 200 + (t >> 4);
        *(unsigned*)&Ksh[(rr << 6) + (((t & 15) ^ ((rr & 7) << 1)) << 2)] = 0u;
    }
    // zero Vt pad cols 196..215
    for (int i = t; i < 64 * 20; i += 256)
        Vt[(i / 20) * PT + 196 + (i % 20)] = 0;
    __syncthreads();

    // ---- QK^T: 13 n-tiles of 16 positions ----
    f32x4 sc[13];
#pragma unroll
    for (int tl = 0; tl < 13; ++tl) {
        const int kr = (tl << 4) + fr;
        half8 b0 = *(const half8*)&Ksh[(kr << 6) + (((0 + fq) ^ (kr & 7)) << 3)];
        half8 b1 = *(const half8*)&Ksh[(kr << 6) + (((4 + fq) ^ (kr & 7)) << 3)];
        f32x4 z = {0.f, 0.f, 0.f, 0.f};
        z = __builtin_amdgcn_mfma_f32_16x16x32_f16(a0, b0, z, 0, 0, 0);
        sc[tl] = __builtin_amdgcn_mfma_f32_16x16x32_f16(a1, b1, z, 0, 0, 0);
    }

    // ---- mask + softmax ----
    float mx[4] = {-3e38f, -3e38f, -3e38f, -3e38f};
#pragma unroll
    for (int tl = 0; tl < 13; ++tl) {
        const int p = (tl << 4) + fr;
        const int pi = p / 14, pj = p - pi * 14;
        const bool pvld = p < 196;
#pragma unroll
        for (int r = 0; r < 4; ++r) {
            const int q = (wave << 4) + (fq << 2) + r;
            const int di = pi - 3 - ((q >> 3) & 7), dj = pj - 3 - (q & 7);
            const bool win = pvld & ((unsigned)(di + 3) <= 6u) & ((unsigned)(dj + 3) <= 6u);
            const float rel = sqrtf((float)(di * di + dj * dj));
            const float mk = sigm((wd[r] - rel) * sh[r]);
            float s = sc[tl][r] * 0.125f - (1.f - mk) * 10000.f;
            s = win ? s : -3e38f;
            sc[tl][r] = s;
            mx[r] = fmaxf(mx[r], s);
        }
    }
#pragma unroll
    for (int r = 0; r < 4; ++r) {
        mx[r] = fmaxf(mx[r], __shfl_xor(mx[r], 1));
        mx[r] = fmaxf(mx[r], __shfl_xor(mx[r], 2));
        mx[r] = fmaxf(mx[r], __shfl_xor(mx[r], 4));
        mx[r] = fmaxf(mx[r], __shfl_xor(mx[r], 8));
    }
    float sm[4] = {0.f, 0.f, 0.f, 0.f};
#pragma unroll
    for (int tl = 0; tl < 13; ++tl)
#pragma unroll
        for (int r = 0; r < 4; ++r) {
            const float e = __expf(sc[tl][r] - mx[r]);
            sc[tl][r] = e; sm[r] += e;
        }
#pragma unroll
    for (int r = 0; r < 4; ++r) {
        sm[r] += __shfl_xor(sm[r], 1);
        sm[r] += __shfl_xor(sm[r], 2);
        sm[r] += __shfl_xor(sm[r], 4);
        sm[r] += __shfl_xor(sm[r], 8);
        sm[r] = 1.f / sm[r];
    }

    __syncthreads();   // Ksh frag reads done before P overwrites
#pragma unroll
    for (int tl = 0; tl < 13; ++tl)
#pragma unroll
        for (int r = 0; r < 4; ++r) {
            __half pv = __float2half(sc[tl][r] * sm[r]);
            Psh[((wave << 4) + (fq << 2) + r) * PT + (tl << 4) + fr] = *(short*)&pv;
        }
    __syncthreads();

    // ---- PV: K = 192 (6x32) + 16 ----
    f32x4 o[4] = {};
    const int pra = (wave << 4) + fr;
#pragma unroll
    for (int s = 0; s < 6; ++s) {
        half8 pa = *(const half8*)&Psh[pra * PT + (fq << 3) + (s << 5)];
#pragma unroll
        for (int dt = 0; dt < 4; ++dt) {
            half8 vbf = *(const half8*)&Vt[((dt << 4) + fr) * PT + (fq << 3) + (s << 5)];
            o[dt] = __builtin_amdgcn_mfma_f32_16x16x32_f16(pa, vbf, o[dt], 0, 0, 0);
        }
    }
    {
        half4 pa = *(const half4*)&Psh[pra * PT + 192 + (fq << 2)];
#pragma unroll
        for (int dt = 0; dt < 4; ++dt) {
            half4 vbf = *(const half4*)&Vt[((dt << 4) + fr) * PT + 192 + (fq << 2)];
            o[dt] = __builtin_amdgcn_mfma_f32_16x16x16f16(pa, vbf, o[dt], 0, 0, 0);
        }
    }

#pragma unroll
    for (int r = 0; r < 4; ++r) {
        float ss = o[0][r]*o[0][r] + o[1][r]*o[1][r] + o[2][r]*o[2][r] + o[3][r]*o[3][r];
        ss += __shfl_xor(ss, 1); ss += __shfl_xor(ss, 2);
        ss += __shfl_xor(ss, 4); ss += __shfl_xor(ss, 8);
        const size_t rowb = (((size_t)(b << 12) + lq[r]) << 8) + h * 64;
#pragma unroll
        for (int dt = 0; dt < 4; ++dt)
            attn_o[rowb + (dt << 4) + fr] = o[dt][r];
        if (fr == 0) sumsq4[(((b << 12) + lq[r]) << 2) + h] = ss;
    }
}

extern "C" void kernel_launch(void* const* d_in, const int* in_sizes, int n_in,
                              void* d_out, int out_size, void* d_ws, size_t ws_size,
                              hipStream_t stream)
{
    const float* x      = (const float*)d_in[0];
    const float* W_qkv  = (const float*)d_in[1];
    const float* w_qn   = (const float*)d_in[2];
    const float* w_kn   = (const float*)d_in[3];
    const float* W_wp   = (const float*)d_in[4];
    const float* b_wp   = (const float*)d_in[5];
    const float* w_on   = (const float*)d_in[6];
    const float* W_out  = (const float*)d_in[7];
    const float* W_gate = (const float*)d_in[8];
    const float* b_gate = (const float*)d_in[9];
    float* out = (float*)d_out;

    __half* ws16 = (__half*)d_ws;
    __half* xh  = ws16;                    // [8][8192][32]
    __half* wqh = xh  + 2097152;           // [8][768][32]
    __half* wql = wqh + 196608;
    __half* wgh = wql + 196608;            // [8][256][32]
    __half* wgl = wgh + 65536;
    __half* woh = wgl + 65536;
    __half* wol = woh + 65536;
    __half* qhp = wol + 65536;             // [8192][256]
    __half* khp = qhp + 2097152;
    __half* vhp = khp + 2097152;
    __half* mh  = vhp + 2097152;
    float* attn_o = (float*)(mh + 2097152);  // [8192][256] f32
    float* widthp = attn_o + 2097152;
    float* sharpp = widthp + 32768;
    float* sumsq4 = sharpp + 32768;

    // x -> f16 blocked + wp; weights -> transposed f16 hi/lo blocked
    prep_kernel<<<304, 256, 0, stream>>>(x, W_qkv, W_gate, W_out, W_wp, b_wp,
                                         xh, wqh, wql, wgh, wgl, woh, wol,
                                         widthp, sharpp);
    // qkv GEMM (2-term) + fused silu/rmsnorm/rope -> q,k,v f16
    gemm_qkv<<<dim3(6, 64), 256, 0, stream>>>(xh, wqh, wql, w_qn, w_kn,
                                              qhp, khp, vhp);
    // patch-GEMM local attention (raw O + sumsq)
    attn_mfma<<<dim3(64, 4, 2), 256, 0, stream>>>(qhp, khp, vhp, widthp, sharpp,
                                                  attn_o, sumsq4);
    // gate gemm + fused o-rmsnorm + merge -> merged f16
    gemm_gate<<<dim3(2, 128), 256, 0, stream>>>(vhp, wgh, wgl, b_gate,
                                                attn_o, sumsq4, w_on, mh);
    // final silu(merged @ W_out)
    gemm_out<<<dim3(2, 128), 256, 0, stream>>>(mh, woh, wol, out);
}